// Round 1
// baseline (1373.762 us; speedup 1.0000x reference)
//
#include <hip/hip_runtime.h>
#include <math.h>

#define NN 51200
#define EE 1638400
#define GG 512
#define INF 16
#define HCC 128

// ---------------- CSR build ----------------
__global__ void k_zero(int* __restrict__ deg) {
    int t = blockIdx.x * 256 + threadIdx.x;
    if (t < NN) deg[t] = 0;
}

__global__ void k_deg(const int* __restrict__ ei, int* __restrict__ deg) {
    int e = blockIdx.x * 256 + threadIdx.x;
    if (e < EE) atomicAdd(&deg[ei[EE + e]], 1);
}

__global__ __launch_bounds__(1024) void k_scan(const int* __restrict__ deg,
                                               int* __restrict__ rowptr,
                                               int* __restrict__ wptr) {
    __shared__ int part[1024];
    int t = threadIdx.x;
    const int CH = NN / 1024;  // 50
    int s = 0;
    for (int i = 0; i < CH; i++) s += deg[t * CH + i];
    part[t] = s;
    __syncthreads();
    for (int off = 1; off < 1024; off <<= 1) {
        int v = part[t];
        int u = (t >= off) ? part[t - off] : 0;
        __syncthreads();
        part[t] = v + u;
        __syncthreads();
    }
    int run = part[t] - s;  // exclusive
    for (int i = 0; i < CH; i++) {
        int idx = t * CH + i;
        int d = deg[idx];
        rowptr[idx] = run;
        wptr[idx] = run;
        run += d;
    }
    if (t == 1023) rowptr[NN] = run;
}

__global__ void k_fill(const int* __restrict__ ei, int* __restrict__ wptr,
                       int* __restrict__ col) {
    int e = blockIdx.x * 256 + threadIdx.x;
    if (e < EE) {
        int d = ei[EE + e];
        int slot = atomicAdd(&wptr[d], 1);
        col[slot] = ei[e];
    }
}

// ---------------- layer-1 linear: x[N,16] @ W[16,128] + b ----------------
__global__ __launch_bounds__(256) void k_lin1(const float* __restrict__ x,
                                              const float* __restrict__ Wl,
                                              const float* __restrict__ bl,
                                              const float* __restrict__ Wr,
                                              const float* __restrict__ br,
                                              float* __restrict__ xl,
                                              float* __restrict__ xr) {
    __shared__ float sx[2][INF];
    int j = threadIdx.x & 127;
    int ty = threadIdx.x >> 7;
    int row = blockIdx.x * 2 + ty;
    if (threadIdx.x < 32) {
        int r = blockIdx.x * 2 + (threadIdx.x >> 4);
        sx[threadIdx.x >> 4][threadIdx.x & 15] = x[(size_t)r * INF + (threadIdx.x & 15)];
    }
    __syncthreads();
    float al = bl[j], ar = br[j];
#pragma unroll
    for (int k = 0; k < INF; k++) {
        float xv = sx[ty][k];
        al = fmaf(xv, Wl[k * HCC + j], al);
        ar = fmaf(xv, Wr[k * HCC + j], ar);
    }
    xl[(size_t)row * HCC + j] = al;
    xr[(size_t)row * HCC + j] = ar;
}

// ---------------- layer-2 linear: h[N,128] @ W[128,128] + b ----------------
// thread j holds W column (128 VGPRs); h row read via wave-uniform pointer
// (scalar loads); 64 rows per block to amortize the W load.
__global__ __launch_bounds__(128) void k_lin2(const float* __restrict__ hin,
                                              const float* __restrict__ Wl,
                                              const float* __restrict__ bl,
                                              const float* __restrict__ Wr,
                                              const float* __restrict__ br,
                                              float* __restrict__ outl,
                                              float* __restrict__ outr) {
    int j = threadIdx.x;
    const float* W = (blockIdx.y == 0) ? Wl : Wr;
    const float* b = (blockIdx.y == 0) ? bl : br;
    float* out = (blockIdx.y == 0) ? outl : outr;
    float w[HCC];
#pragma unroll
    for (int k = 0; k < HCC; k++) w[k] = W[k * HCC + j];
    float bj = b[j];
    int r0 = blockIdx.x * 64;
    for (int r = 0; r < 64; r++) {
        const float4* hp4 = (const float4*)(hin + (size_t)(r0 + r) * HCC);
        float a0 = 0.f, a1 = 0.f, a2 = 0.f, a3 = 0.f;
#pragma unroll
        for (int k4 = 0; k4 < HCC / 4; k4++) {
            float4 hv = hp4[k4];
            a0 = fmaf(hv.x, w[4 * k4 + 0], a0);
            a1 = fmaf(hv.y, w[4 * k4 + 1], a1);
            a2 = fmaf(hv.z, w[4 * k4 + 2], a2);
            a3 = fmaf(hv.w, w[4 * k4 + 3], a3);
        }
        out[(size_t)(r0 + r) * HCC + j] = bj + ((a0 + a1) + (a2 + a3));
    }
}

// ---------------- GATv2 attention + aggregate, one wave per node ----------
// lane holds channels (2*lane, 2*lane+1); head group = 16 consecutive lanes.
__global__ __launch_bounds__(256) void k_attn(const int* __restrict__ rowptr,
                                              const int* __restrict__ col,
                                              const float* __restrict__ xl,
                                              const float* __restrict__ xr,
                                              const float* __restrict__ att,
                                              const float* __restrict__ bias,
                                              float* __restrict__ hout) {
    int wave = threadIdx.x >> 6;
    int lane = threadIdx.x & 63;
    int n = blockIdx.x * 4 + wave;
    const float2* xl2 = (const float2*)xl;
    const float2* xr2 = (const float2*)xr;
    float2 xrv = xr2[(size_t)n * 64 + lane];
    float2 attv = ((const float2*)att)[lane];
    int base = rowptr[n];
    int deg = rowptr[n + 1] - base;
    float m = -INFINITY, l = 0.f, accx = 0.f, accy = 0.f;
    for (int i0 = 0; i0 < deg; i0 += 64) {
        int mye = 0;
        if (i0 + lane < deg) mye = col[base + i0 + lane];
        int cnt = min(64, deg - i0);
        for (int jj = 0; jj < cnt; ++jj) {
            int src = __shfl(mye, jj);
            float2 v = xl2[(size_t)src * 64 + lane];
            float e0 = v.x + xrv.x; e0 = (e0 > 0.f) ? e0 : 0.2f * e0;
            float e1 = v.y + xrv.y; e1 = (e1 > 0.f) ? e1 : 0.2f * e1;
            float p = fmaf(e0, attv.x, e1 * attv.y);
            p += __shfl_xor(p, 1);
            p += __shfl_xor(p, 2);
            p += __shfl_xor(p, 4);
            p += __shfl_xor(p, 8);
            float mn = fmaxf(m, p);
            float sc = __expf(m - mn);   // m=-inf first iter -> 0
            float wgt = __expf(p - mn);
            l = l * sc + wgt;
            accx = fmaf(accx, sc, wgt * v.x);
            accy = fmaf(accy, sc, wgt * v.y);
            m = mn;
        }
    }
    float inv = 1.f / (l + 1e-16f);
    float ox = fmaf(accx, inv, bias[2 * lane]);
    float oy = fmaf(accy, inv, bias[2 * lane + 1]);
    ox = fmaxf(ox, 0.f);
    oy = fmaxf(oy, 0.f);
    float2 o; o.x = ox; o.y = oy;
    ((float2*)hout)[(size_t)n * 64 + lane] = o;
}

// ---------------- pool (sorted batch) + MLP head ----------------
__global__ __launch_bounds__(128) void k_head(const float* __restrict__ h,
                                              const int* __restrict__ batch,
                                              const float* __restrict__ fc1W, const float* __restrict__ fc1b,
                                              const float* __restrict__ bn1g, const float* __restrict__ bn1b,
                                              const float* __restrict__ fc2W, const float* __restrict__ fc2b,
                                              const float* __restrict__ bn2g, const float* __restrict__ bn2b,
                                              const float* __restrict__ fc3W, const float* __restrict__ fc3b,
                                              float* __restrict__ out) {
    int g = blockIdx.x;
    int j = threadIdx.x;
    __shared__ float buf[HCC], buf2[HCC];
    // lower_bound(g) and lower_bound(g+1) over sorted batch
    int lo = 0, hi = NN;
    while (lo < hi) { int mid = (lo + hi) >> 1; if (batch[mid] < g) lo = mid + 1; else hi = mid; }
    int s = lo;
    lo = 0; hi = NN;
    while (lo < hi) { int mid = (lo + hi) >> 1; if (batch[mid] < g + 1) lo = mid + 1; else hi = mid; }
    int e = lo;
    float sum = 0.f;
    for (int n = s; n < e; n++) sum += h[(size_t)n * HCC + j];
    float cnt = (float)(e - s);
    buf[j] = sum / fmaxf(cnt, 1.0f);
    __syncthreads();
    const float SQ = 1.00000499998749994f;  // np.sqrt(1+1e-5) as f32
    float a = fc1b[j];
    for (int k = 0; k < HCC; k++) a = fmaf(buf[k], fc1W[k * HCC + j], a);
    a = fmaf(a, bn1g[j] / SQ, bn1b[j]);
    a = fmaxf(a, 0.f);
    buf2[j] = a;
    __syncthreads();
    a = fc2b[j];
    for (int k = 0; k < HCC; k++) a = fmaf(buf2[k], fc2W[k * HCC + j], a);
    a = fmaf(a, bn2g[j] / SQ, bn2b[j]);
    a = fmaxf(a, 0.f);
    buf[j] = a;
    __syncthreads();
    if (j < 2) {
        float o = fc3b[j];
        for (int k = 0; k < HCC; k++) o = fmaf(buf[k], fc3W[k * 2 + j], o);
        out[g * 2 + j] = o;
    }
}

extern "C" void kernel_launch(void* const* d_in, const int* in_sizes, int n_in,
                              void* d_out, int out_size, void* d_ws, size_t ws_size,
                              hipStream_t stream) {
    const float* x      = (const float*)d_in[0];
    const int*   ei     = (const int*)d_in[1];
    const int*   batch  = (const int*)d_in[2];
    const float* l1_Wl  = (const float*)d_in[3];
    const float* l1_bl  = (const float*)d_in[4];
    const float* l1_Wr  = (const float*)d_in[5];
    const float* l1_br  = (const float*)d_in[6];
    const float* l1_att = (const float*)d_in[7];
    const float* l1_bias= (const float*)d_in[8];
    const float* l2_Wl  = (const float*)d_in[9];
    const float* l2_bl  = (const float*)d_in[10];
    const float* l2_Wr  = (const float*)d_in[11];
    const float* l2_br  = (const float*)d_in[12];
    const float* l2_att = (const float*)d_in[13];
    const float* l2_bias= (const float*)d_in[14];
    const float* fc1_W  = (const float*)d_in[15];
    const float* fc1_b  = (const float*)d_in[16];
    const float* bn1_g  = (const float*)d_in[17];
    const float* bn1_b  = (const float*)d_in[18];
    const float* fc2_W  = (const float*)d_in[19];
    const float* fc2_b  = (const float*)d_in[20];
    const float* bn2_g  = (const float*)d_in[21];
    const float* bn2_b  = (const float*)d_in[22];
    const float* fc3_W  = (const float*)d_in[23];
    const float* fc3_b  = (const float*)d_in[24];
    float* out = (float*)d_out;

    float* xl = (float*)d_ws;
    float* xr = xl + (size_t)NN * HCC;
    float* h  = xr + (size_t)NN * HCC;
    int* deg    = (int*)(h + (size_t)NN * HCC);
    int* wptr   = deg + NN;
    int* rowptr = wptr + NN;
    int* col    = rowptr + (NN + 1);

    // CSR build
    k_zero<<<NN / 256, 256, 0, stream>>>(deg);
    k_deg<<<EE / 256, 256, 0, stream>>>(ei, deg);
    k_scan<<<1, 1024, 0, stream>>>(deg, rowptr, wptr);
    k_fill<<<EE / 256, 256, 0, stream>>>(ei, wptr, col);

    // layer 1
    k_lin1<<<NN / 2, 256, 0, stream>>>(x, l1_Wl, l1_bl, l1_Wr, l1_br, xl, xr);
    k_attn<<<NN / 4, 256, 0, stream>>>(rowptr, col, xl, xr, l1_att, l1_bias, h);

    // layer 2
    dim3 g2(NN / 64, 2);
    k_lin2<<<g2, 128, 0, stream>>>(h, l2_Wl, l2_bl, l2_Wr, l2_br, xl, xr);
    k_attn<<<NN / 4, 256, 0, stream>>>(rowptr, col, xl, xr, l2_att, l2_bias, h);

    // pool + MLP head
    k_head<<<GG, 128, 0, stream>>>(h, batch, fc1_W, fc1_b, bn1_g, bn1_b,
                                   fc2_W, fc2_b, bn2_g, bn2_b, fc3_W, fc3_b, out);
}

// Round 2
// 770.503 us; speedup vs baseline: 1.7829x; 1.7829x over previous
//
#include <hip/hip_runtime.h>
#include <math.h>

#define NN 51200
#define EE 1638400
#define GG 512
#define INF 16
#define HCC 128

// ---------------- CSR build ----------------
__global__ void k_zero(int* __restrict__ deg) {
    int t = blockIdx.x * 256 + threadIdx.x;
    if (t < NN) deg[t] = 0;
}

__global__ void k_deg(const int* __restrict__ ei, int* __restrict__ deg) {
    int e = blockIdx.x * 256 + threadIdx.x;
    if (e < EE) atomicAdd(&deg[ei[EE + e]], 1);
}

__global__ __launch_bounds__(1024) void k_scan(const int* __restrict__ deg,
                                               int* __restrict__ rowptr,
                                               int* __restrict__ wptr) {
    __shared__ int part[1024];
    int t = threadIdx.x;
    const int CH = NN / 1024;  // 50
    int s = 0;
    for (int i = 0; i < CH; i++) s += deg[t * CH + i];
    part[t] = s;
    __syncthreads();
    for (int off = 1; off < 1024; off <<= 1) {
        int v = part[t];
        int u = (t >= off) ? part[t - off] : 0;
        __syncthreads();
        part[t] = v + u;
        __syncthreads();
    }
    int run = part[t] - s;  // exclusive
    for (int i = 0; i < CH; i++) {
        int idx = t * CH + i;
        int d = deg[idx];
        rowptr[idx] = run;
        wptr[idx] = run;
        run += d;
    }
    if (t == 1023) rowptr[NN] = run;
}

__global__ void k_fill(const int* __restrict__ ei, int* __restrict__ wptr,
                       int* __restrict__ col) {
    int e = blockIdx.x * 256 + threadIdx.x;
    if (e < EE) {
        int d = ei[EE + e];
        int slot = atomicAdd(&wptr[d], 1);
        col[slot] = ei[e];
    }
}

// ---------------- layer-1 linear: x[N,16] @ W[16,128] + b ----------------
__global__ __launch_bounds__(256) void k_lin1(const float* __restrict__ x,
                                              const float* __restrict__ Wl,
                                              const float* __restrict__ bl,
                                              const float* __restrict__ Wr,
                                              const float* __restrict__ br,
                                              float* __restrict__ xl,
                                              float* __restrict__ xr) {
    __shared__ float sx[2][INF];
    int j = threadIdx.x & 127;
    int ty = threadIdx.x >> 7;
    int row = blockIdx.x * 2 + ty;
    if (threadIdx.x < 32) {
        int r = blockIdx.x * 2 + (threadIdx.x >> 4);
        sx[threadIdx.x >> 4][threadIdx.x & 15] = x[(size_t)r * INF + (threadIdx.x & 15)];
    }
    __syncthreads();
    float al = bl[j], ar = br[j];
#pragma unroll
    for (int k = 0; k < INF; k++) {
        float xv = sx[ty][k];
        al = fmaf(xv, Wl[k * HCC + j], al);
        ar = fmaf(xv, Wr[k * HCC + j], ar);
    }
    xl[(size_t)row * HCC + j] = al;
    xr[(size_t)row * HCC + j] = ar;
}

// ---------------- layer-2 linear: h[N,128] @ {Wl,Wr}[128,128] + b ----------
// LDS-tiled GEMM. Block tile: 128 rows x 256 cols (Wl||Wr fused, h read once).
// 512 threads; thread = (cx 0..31, cy 0..15): 8 rows (cy+16j) x 4 Wl cols +
// 4 Wr cols (both = cols 4cx..4cx+3 of the respective output).
#define AST 129   // As stride (dwords): breaks staging-write bank conflicts
#define BST 260   // Bs stride (dwords): keeps float4 rows aligned
__global__ __launch_bounds__(512) void k_lin2(const float* __restrict__ hin,
                                              const float* __restrict__ Wl,
                                              const float* __restrict__ bl,
                                              const float* __restrict__ Wr,
                                              const float* __restrict__ br,
                                              float* __restrict__ outl,
                                              float* __restrict__ outr) {
    __shared__ float As[32 * AST];   // K-major: As[k][row], 16.5 KB
    __shared__ float Bs[32 * BST];   // Bs[k][c], c<128 Wl, c>=128 Wr, 33.3 KB
    const int tid = threadIdx.x;
    const int cx = tid & 31;   // col group: cols 4cx..4cx+3
    const int cy = tid >> 5;   // row group: rows cy+16j, j=0..7
    const int r0 = blockIdx.x * 128;

    float accL[8][4], accR[8][4];
#pragma unroll
    for (int j = 0; j < 8; j++)
#pragma unroll
        for (int i = 0; i < 4; i++) { accL[j][i] = 0.f; accR[j][i] = 0.f; }

    for (int k0 = 0; k0 < HCC; k0 += 32) {
        // stage A: 128 rows x 32 k = 1024 float4, 2 per thread, transposed
#pragma unroll
        for (int s = 0; s < 2; s++) {
            int f = tid + 512 * s;
            int row = f >> 3;
            int kk = (f & 7) * 4;
            float4 v = *(const float4*)(hin + (size_t)(r0 + row) * HCC + k0 + kk);
            As[(kk + 0) * AST + row] = v.x;
            As[(kk + 1) * AST + row] = v.y;
            As[(kk + 2) * AST + row] = v.z;
            As[(kk + 3) * AST + row] = v.w;
        }
        // stage B: 32 k x 256 c = 2048 float4, 4 per thread
#pragma unroll
        for (int s = 0; s < 4; s++) {
            int g = tid + 512 * s;
            int kr = g >> 6;
            int c4 = g & 63;
            const float* srcp = (c4 < 32)
                ? (Wl + (size_t)(k0 + kr) * HCC + c4 * 4)
                : (Wr + (size_t)(k0 + kr) * HCC + (c4 - 32) * 4);
            *(float4*)&Bs[kr * BST + c4 * 4] = *(const float4*)srcp;
        }
        __syncthreads();
#pragma unroll 4
        for (int k = 0; k < 32; ++k) {
            float a[8];
#pragma unroll
            for (int j = 0; j < 8; ++j) a[j] = As[k * AST + cy + 16 * j];
            float4 b4l = *(const float4*)&Bs[k * BST + cx * 4];
            float4 b4r = *(const float4*)&Bs[k * BST + 128 + cx * 4];
#pragma unroll
            for (int j = 0; j < 8; ++j) {
                accL[j][0] = fmaf(a[j], b4l.x, accL[j][0]);
                accL[j][1] = fmaf(a[j], b4l.y, accL[j][1]);
                accL[j][2] = fmaf(a[j], b4l.z, accL[j][2]);
                accL[j][3] = fmaf(a[j], b4l.w, accL[j][3]);
                accR[j][0] = fmaf(a[j], b4r.x, accR[j][0]);
                accR[j][1] = fmaf(a[j], b4r.y, accR[j][1]);
                accR[j][2] = fmaf(a[j], b4r.z, accR[j][2]);
                accR[j][3] = fmaf(a[j], b4r.w, accR[j][3]);
            }
        }
        __syncthreads();
    }
    float4 bv_l = *(const float4*)(bl + cx * 4);
    float4 bv_r = *(const float4*)(br + cx * 4);
#pragma unroll
    for (int j = 0; j < 8; ++j) {
        int row = r0 + cy + 16 * j;
        float4 o;
        o.x = accL[j][0] + bv_l.x;
        o.y = accL[j][1] + bv_l.y;
        o.z = accL[j][2] + bv_l.z;
        o.w = accL[j][3] + bv_l.w;
        *(float4*)(outl + (size_t)row * HCC + cx * 4) = o;
        o.x = accR[j][0] + bv_r.x;
        o.y = accR[j][1] + bv_r.y;
        o.z = accR[j][2] + bv_r.z;
        o.w = accR[j][3] + bv_r.w;
        *(float4*)(outr + (size_t)row * HCC + cx * 4) = o;
    }
}

// ---------------- GATv2 attention + aggregate, one wave per node ----------
// lane holds channels (2*lane, 2*lane+1); head group = 16 consecutive lanes.
__global__ __launch_bounds__(256) void k_attn(const int* __restrict__ rowptr,
                                              const int* __restrict__ col,
                                              const float* __restrict__ xl,
                                              const float* __restrict__ xr,
                                              const float* __restrict__ att,
                                              const float* __restrict__ bias,
                                              float* __restrict__ hout) {
    int wave = threadIdx.x >> 6;
    int lane = threadIdx.x & 63;
    int n = blockIdx.x * 4 + wave;
    const float2* xl2 = (const float2*)xl;
    const float2* xr2 = (const float2*)xr;
    float2 xrv = xr2[(size_t)n * 64 + lane];
    float2 attv = ((const float2*)att)[lane];
    int base = rowptr[n];
    int deg = rowptr[n + 1] - base;
    float m = -INFINITY, l = 0.f, accx = 0.f, accy = 0.f;
    for (int i0 = 0; i0 < deg; i0 += 64) {
        int mye = 0;
        if (i0 + lane < deg) mye = col[base + i0 + lane];
        int cnt = min(64, deg - i0);
        for (int jj = 0; jj < cnt; ++jj) {
            int src = __shfl(mye, jj);
            float2 v = xl2[(size_t)src * 64 + lane];
            float e0 = v.x + xrv.x; e0 = (e0 > 0.f) ? e0 : 0.2f * e0;
            float e1 = v.y + xrv.y; e1 = (e1 > 0.f) ? e1 : 0.2f * e1;
            float p = fmaf(e0, attv.x, e1 * attv.y);
            p += __shfl_xor(p, 1);
            p += __shfl_xor(p, 2);
            p += __shfl_xor(p, 4);
            p += __shfl_xor(p, 8);
            float mn = fmaxf(m, p);
            float sc = __expf(m - mn);   // m=-inf first iter -> 0
            float wgt = __expf(p - mn);
            l = l * sc + wgt;
            accx = fmaf(accx, sc, wgt * v.x);
            accy = fmaf(accy, sc, wgt * v.y);
            m = mn;
        }
    }
    float inv = 1.f / (l + 1e-16f);
    float ox = fmaf(accx, inv, bias[2 * lane]);
    float oy = fmaf(accy, inv, bias[2 * lane + 1]);
    ox = fmaxf(ox, 0.f);
    oy = fmaxf(oy, 0.f);
    float2 o; o.x = ox; o.y = oy;
    ((float2*)hout)[(size_t)n * 64 + lane] = o;
}

// ---------------- pool (sorted batch) + MLP head ----------------
__global__ __launch_bounds__(128) void k_head(const float* __restrict__ h,
                                              const int* __restrict__ batch,
                                              const float* __restrict__ fc1W, const float* __restrict__ fc1b,
                                              const float* __restrict__ bn1g, const float* __restrict__ bn1b,
                                              const float* __restrict__ fc2W, const float* __restrict__ fc2b,
                                              const float* __restrict__ bn2g, const float* __restrict__ bn2b,
                                              const float* __restrict__ fc3W, const float* __restrict__ fc3b,
                                              float* __restrict__ out) {
    int g = blockIdx.x;
    int j = threadIdx.x;
    __shared__ float buf[HCC], buf2[HCC];
    int lo = 0, hi = NN;
    while (lo < hi) { int mid = (lo + hi) >> 1; if (batch[mid] < g) lo = mid + 1; else hi = mid; }
    int s = lo;
    lo = 0; hi = NN;
    while (lo < hi) { int mid = (lo + hi) >> 1; if (batch[mid] < g + 1) lo = mid + 1; else hi = mid; }
    int e = lo;
    float sum = 0.f;
    for (int n = s; n < e; n++) sum += h[(size_t)n * HCC + j];
    float cnt = (float)(e - s);
    buf[j] = sum / fmaxf(cnt, 1.0f);
    __syncthreads();
    const float SQ = 1.00000499998749994f;  // np.sqrt(1+1e-5) as f32
    float a = fc1b[j];
    for (int k = 0; k < HCC; k++) a = fmaf(buf[k], fc1W[k * HCC + j], a);
    a = fmaf(a, bn1g[j] / SQ, bn1b[j]);
    a = fmaxf(a, 0.f);
    buf2[j] = a;
    __syncthreads();
    a = fc2b[j];
    for (int k = 0; k < HCC; k++) a = fmaf(buf2[k], fc2W[k * HCC + j], a);
    a = fmaf(a, bn2g[j] / SQ, bn2b[j]);
    a = fmaxf(a, 0.f);
    buf[j] = a;
    __syncthreads();
    if (j < 2) {
        float o = fc3b[j];
        for (int k = 0; k < HCC; k++) o = fmaf(buf[k], fc3W[k * 2 + j], o);
        out[g * 2 + j] = o;
    }
}

extern "C" void kernel_launch(void* const* d_in, const int* in_sizes, int n_in,
                              void* d_out, int out_size, void* d_ws, size_t ws_size,
                              hipStream_t stream) {
    const float* x      = (const float*)d_in[0];
    const int*   ei     = (const int*)d_in[1];
    const int*   batch  = (const int*)d_in[2];
    const float* l1_Wl  = (const float*)d_in[3];
    const float* l1_bl  = (const float*)d_in[4];
    const float* l1_Wr  = (const float*)d_in[5];
    const float* l1_br  = (const float*)d_in[6];
    const float* l1_att = (const float*)d_in[7];
    const float* l1_bias= (const float*)d_in[8];
    const float* l2_Wl  = (const float*)d_in[9];
    const float* l2_bl  = (const float*)d_in[10];
    const float* l2_Wr  = (const float*)d_in[11];
    const float* l2_br  = (const float*)d_in[12];
    const float* l2_att = (const float*)d_in[13];
    const float* l2_bias= (const float*)d_in[14];
    const float* fc1_W  = (const float*)d_in[15];
    const float* fc1_b  = (const float*)d_in[16];
    const float* bn1_g  = (const float*)d_in[17];
    const float* bn1_b  = (const float*)d_in[18];
    const float* fc2_W  = (const float*)d_in[19];
    const float* fc2_b  = (const float*)d_in[20];
    const float* bn2_g  = (const float*)d_in[21];
    const float* bn2_b  = (const float*)d_in[22];
    const float* fc3_W  = (const float*)d_in[23];
    const float* fc3_b  = (const float*)d_in[24];
    float* out = (float*)d_out;

    float* xl = (float*)d_ws;
    float* xr = xl + (size_t)NN * HCC;
    float* h  = xr + (size_t)NN * HCC;
    int* deg    = (int*)(h + (size_t)NN * HCC);
    int* wptr   = deg + NN;
    int* rowptr = wptr + NN;
    int* col    = rowptr + (NN + 1);

    // CSR build
    k_zero<<<NN / 256, 256, 0, stream>>>(deg);
    k_deg<<<EE / 256, 256, 0, stream>>>(ei, deg);
    k_scan<<<1, 1024, 0, stream>>>(deg, rowptr, wptr);
    k_fill<<<EE / 256, 256, 0, stream>>>(ei, wptr, col);

    // layer 1
    k_lin1<<<NN / 2, 256, 0, stream>>>(x, l1_Wl, l1_bl, l1_Wr, l1_br, xl, xr);
    k_attn<<<NN / 4, 256, 0, stream>>>(rowptr, col, xl, xr, l1_att, l1_bias, h);

    // layer 2
    k_lin2<<<NN / 128, 512, 0, stream>>>(h, l2_Wl, l2_bl, l2_Wr, l2_br, xl, xr);
    k_attn<<<NN / 4, 256, 0, stream>>>(rowptr, col, xl, xr, l2_att, l2_bias, h);

    // pool + MLP head
    k_head<<<GG, 128, 0, stream>>>(h, batch, fc1_W, fc1_b, bn1_g, bn1_b,
                                   fc2_W, fc2_b, bn2_g, bn2_b, fc3_W, fc3_b, out);
}

// Round 3
// 686.333 us; speedup vs baseline: 2.0016x; 1.1226x over previous
//
#include <hip/hip_runtime.h>
#include <math.h>

#define NN 51200
#define EE 1638400
#define GG 512
#define INF 16
#define HCC 128

// ---------------- CSR build ----------------
__global__ void k_zero(int* __restrict__ deg) {
    int t = blockIdx.x * 256 + threadIdx.x;
    if (t < NN) deg[t] = 0;
}

__global__ void k_deg(const int* __restrict__ ei, int* __restrict__ deg) {
    int e = blockIdx.x * 256 + threadIdx.x;
    if (e < EE) atomicAdd(&deg[ei[EE + e]], 1);
}

__global__ __launch_bounds__(1024) void k_scan(const int* __restrict__ deg,
                                               int* __restrict__ rowptr,
                                               int* __restrict__ wptr) {
    __shared__ int part[1024];
    int t = threadIdx.x;
    const int CH = NN / 1024;  // 50
    int s = 0;
    for (int i = 0; i < CH; i++) s += deg[t * CH + i];
    part[t] = s;
    __syncthreads();
    for (int off = 1; off < 1024; off <<= 1) {
        int v = part[t];
        int u = (t >= off) ? part[t - off] : 0;
        __syncthreads();
        part[t] = v + u;
        __syncthreads();
    }
    int run = part[t] - s;  // exclusive
    for (int i = 0; i < CH; i++) {
        int idx = t * CH + i;
        int d = deg[idx];
        rowptr[idx] = run;
        wptr[idx] = run;
        run += d;
    }
    if (t == 1023) rowptr[NN] = run;
}

__global__ void k_fill(const int* __restrict__ ei, int* __restrict__ wptr,
                       int* __restrict__ col) {
    int e = blockIdx.x * 256 + threadIdx.x;
    if (e < EE) {
        int d = ei[EE + e];
        int slot = atomicAdd(&wptr[d], 1);
        col[slot] = ei[e];
    }
}

// ---------------- layer-1 linear: x[N,16] @ W[16,128] + b ----------------
__global__ __launch_bounds__(256) void k_lin1(const float* __restrict__ x,
                                              const float* __restrict__ Wl,
                                              const float* __restrict__ bl,
                                              const float* __restrict__ Wr,
                                              const float* __restrict__ br,
                                              float* __restrict__ xl,
                                              float* __restrict__ xr) {
    __shared__ float sx[2][INF];
    int j = threadIdx.x & 127;
    int ty = threadIdx.x >> 7;
    int row = blockIdx.x * 2 + ty;
    if (threadIdx.x < 32) {
        int r = blockIdx.x * 2 + (threadIdx.x >> 4);
        sx[threadIdx.x >> 4][threadIdx.x & 15] = x[(size_t)r * INF + (threadIdx.x & 15)];
    }
    __syncthreads();
    float al = bl[j], ar = br[j];
#pragma unroll
    for (int k = 0; k < INF; k++) {
        float xv = sx[ty][k];
        al = fmaf(xv, Wl[k * HCC + j], al);
        ar = fmaf(xv, Wr[k * HCC + j], ar);
    }
    xl[(size_t)row * HCC + j] = al;
    xr[(size_t)row * HCC + j] = ar;
}

// ---------------- layer-2 linear: h[N,128] @ {Wl,Wr}[128,128] + b ----------
#define AST 129
#define BST 260
__global__ __launch_bounds__(512) void k_lin2(const float* __restrict__ hin,
                                              const float* __restrict__ Wl,
                                              const float* __restrict__ bl,
                                              const float* __restrict__ Wr,
                                              const float* __restrict__ br,
                                              float* __restrict__ outl,
                                              float* __restrict__ outr) {
    __shared__ float As[32 * AST];
    __shared__ float Bs[32 * BST];
    const int tid = threadIdx.x;
    const int cx = tid & 31;
    const int cy = tid >> 5;
    const int r0 = blockIdx.x * 128;

    float accL[8][4], accR[8][4];
#pragma unroll
    for (int j = 0; j < 8; j++)
#pragma unroll
        for (int i = 0; i < 4; i++) { accL[j][i] = 0.f; accR[j][i] = 0.f; }

    for (int k0 = 0; k0 < HCC; k0 += 32) {
#pragma unroll
        for (int s = 0; s < 2; s++) {
            int f = tid + 512 * s;
            int row = f >> 3;
            int kk = (f & 7) * 4;
            float4 v = *(const float4*)(hin + (size_t)(r0 + row) * HCC + k0 + kk);
            As[(kk + 0) * AST + row] = v.x;
            As[(kk + 1) * AST + row] = v.y;
            As[(kk + 2) * AST + row] = v.z;
            As[(kk + 3) * AST + row] = v.w;
        }
#pragma unroll
        for (int s = 0; s < 4; s++) {
            int g = tid + 512 * s;
            int kr = g >> 6;
            int c4 = g & 63;
            const float* srcp = (c4 < 32)
                ? (Wl + (size_t)(k0 + kr) * HCC + c4 * 4)
                : (Wr + (size_t)(k0 + kr) * HCC + (c4 - 32) * 4);
            *(float4*)&Bs[kr * BST + c4 * 4] = *(const float4*)srcp;
        }
        __syncthreads();
#pragma unroll 4
        for (int k = 0; k < 32; ++k) {
            float a[8];
#pragma unroll
            for (int j = 0; j < 8; ++j) a[j] = As[k * AST + cy + 16 * j];
            float4 b4l = *(const float4*)&Bs[k * BST + cx * 4];
            float4 b4r = *(const float4*)&Bs[k * BST + 128 + cx * 4];
#pragma unroll
            for (int j = 0; j < 8; ++j) {
                accL[j][0] = fmaf(a[j], b4l.x, accL[j][0]);
                accL[j][1] = fmaf(a[j], b4l.y, accL[j][1]);
                accL[j][2] = fmaf(a[j], b4l.z, accL[j][2]);
                accL[j][3] = fmaf(a[j], b4l.w, accL[j][3]);
                accR[j][0] = fmaf(a[j], b4r.x, accR[j][0]);
                accR[j][1] = fmaf(a[j], b4r.y, accR[j][1]);
                accR[j][2] = fmaf(a[j], b4r.z, accR[j][2]);
                accR[j][3] = fmaf(a[j], b4r.w, accR[j][3]);
            }
        }
        __syncthreads();
    }
    float4 bv_l = *(const float4*)(bl + cx * 4);
    float4 bv_r = *(const float4*)(br + cx * 4);
#pragma unroll
    for (int j = 0; j < 8; ++j) {
        int row = r0 + cy + 16 * j;
        float4 o;
        o.x = accL[j][0] + bv_l.x;
        o.y = accL[j][1] + bv_l.y;
        o.z = accL[j][2] + bv_l.z;
        o.w = accL[j][3] + bv_l.w;
        *(float4*)(outl + (size_t)row * HCC + cx * 4) = o;
        o.x = accR[j][0] + bv_r.x;
        o.y = accR[j][1] + bv_r.y;
        o.z = accR[j][2] + bv_r.z;
        o.w = accR[j][3] + bv_r.w;
        *(float4*)(outr + (size_t)row * HCC + cx * 4) = o;
    }
}

// ---------------- GATv2 attention + aggregate, one wave per node ----------
// 2 edges per iteration: sub = lane>>5 picks the edge, sl = lane&31 picks
// the channel slice (float4, channels 4sl..4sl+3). Head = 8 consecutive sl.
// Odd tail handled by forcing the invalid half's score to -inf (weight 0).
__global__ __launch_bounds__(256) void k_attn(const int* __restrict__ rowptr,
                                              const int* __restrict__ col,
                                              const float* __restrict__ xl,
                                              const float* __restrict__ xr,
                                              const float* __restrict__ att,
                                              const float* __restrict__ bias,
                                              float* __restrict__ hout) {
    const int wave = threadIdx.x >> 6;
    const int lane = threadIdx.x & 63;
    const int sub = lane >> 5;       // which edge of the pair
    const int sl = lane & 31;        // channel slice
    const int n = blockIdx.x * 4 + wave;

    const float4 xrv = *(const float4*)(xr + (size_t)n * HCC + sl * 4);
    const float4 attv = *(const float4*)(att + sl * 4);
    const unsigned choff = (unsigned)sl * 16u;   // byte offset within a row

    const int base = rowptr[n];
    const int deg = rowptr[n + 1] - base;

    float m = -INFINITY, l = 0.f;
    float4 acc = {0.f, 0.f, 0.f, 0.f};

    for (int i0 = 0; i0 < deg; i0 += 64) {
        int mye = 0;
        if (i0 + lane < deg) mye = col[base + i0 + lane];
        const int cnt = min(64, deg - i0);
        const int pairs = (cnt + 1) >> 1;
#pragma unroll 2
        for (int jj = 0; jj < pairs; ++jj) {
            const int s0 = __builtin_amdgcn_readlane(mye, 2 * jj);
            const int s1 = __builtin_amdgcn_readlane(mye, 2 * jj + 1);
            const bool valid = (2 * jj + sub) < cnt;
            const unsigned a0 = (unsigned)s0 << 9;   // *512 bytes
            const unsigned a1 = (unsigned)s1 << 9;
            const unsigned voff = (sub ? a1 : a0) + choff;
            const float4 v = *(const float4*)((const char*)xl + voff);
            // leaky-relu(v + xrv) dotted with att slice
            float e0 = v.x + xrv.x, e1 = v.y + xrv.y, e2 = v.z + xrv.z, e3 = v.w + xrv.w;
            float k0 = fmaf(0.2f, fminf(e0, 0.f), fmaxf(e0, 0.f));
            float k1 = fmaf(0.2f, fminf(e1, 0.f), fmaxf(e1, 0.f));
            float k2 = fmaf(0.2f, fminf(e2, 0.f), fmaxf(e2, 0.f));
            float k3 = fmaf(0.2f, fminf(e3, 0.f), fmaxf(e3, 0.f));
            float p = k0 * attv.x;
            p = fmaf(k1, attv.y, p);
            p = fmaf(k2, attv.z, p);
            p = fmaf(k3, attv.w, p);
            // reduce over the head's 8 lanes (same sub half)
            p += __shfl_xor(p, 1);
            p += __shfl_xor(p, 2);
            p += __shfl_xor(p, 4);
            if (!valid) p = -INFINITY;
            // shared max across the pair
            const float pmax = fmaxf(p, __shfl_xor(p, 32));
            const float mn = fmaxf(m, pmax);
            const float sc = __expf(m - mn);     // m=-inf first iter -> 0
            const float wgt = __expf(p - mn);    // invalid -> 0
            l = fmaf(l, sc, wgt);
            acc.x = fmaf(acc.x, sc, wgt * v.x);
            acc.y = fmaf(acc.y, sc, wgt * v.y);
            acc.z = fmaf(acc.z, sc, wgt * v.z);
            acc.w = fmaf(acc.w, sc, wgt * v.w);
            m = mn;
        }
    }
    // combine the two halves (they share the same m)
    l += __shfl_xor(l, 32);
    acc.x += __shfl_xor(acc.x, 32);
    acc.y += __shfl_xor(acc.y, 32);
    acc.z += __shfl_xor(acc.z, 32);
    acc.w += __shfl_xor(acc.w, 32);
    const float inv = 1.f / (l + 1e-16f);
    if (sub == 0) {
        const float4 bv = *(const float4*)(bias + sl * 4);
        float4 o;
        o.x = fmaxf(fmaf(acc.x, inv, bv.x), 0.f);
        o.y = fmaxf(fmaf(acc.y, inv, bv.y), 0.f);
        o.z = fmaxf(fmaf(acc.z, inv, bv.z), 0.f);
        o.w = fmaxf(fmaf(acc.w, inv, bv.w), 0.f);
        *(float4*)(hout + (size_t)n * HCC + sl * 4) = o;
    }
}

// ---------------- pool (sorted batch) + MLP head ----------------
__global__ __launch_bounds__(128) void k_head(const float* __restrict__ h,
                                              const int* __restrict__ batch,
                                              const float* __restrict__ fc1W, const float* __restrict__ fc1b,
                                              const float* __restrict__ bn1g, const float* __restrict__ bn1b,
                                              const float* __restrict__ fc2W, const float* __restrict__ fc2b,
                                              const float* __restrict__ bn2g, const float* __restrict__ bn2b,
                                              const float* __restrict__ fc3W, const float* __restrict__ fc3b,
                                              float* __restrict__ out) {
    int g = blockIdx.x;
    int j = threadIdx.x;
    __shared__ float buf[HCC], buf2[HCC];
    int lo = 0, hi = NN;
    while (lo < hi) { int mid = (lo + hi) >> 1; if (batch[mid] < g) lo = mid + 1; else hi = mid; }
    int s = lo;
    lo = 0; hi = NN;
    while (lo < hi) { int mid = (lo + hi) >> 1; if (batch[mid] < g + 1) lo = mid + 1; else hi = mid; }
    int e = lo;
    float sum = 0.f;
    for (int n = s; n < e; n++) sum += h[(size_t)n * HCC + j];
    float cnt = (float)(e - s);
    buf[j] = sum / fmaxf(cnt, 1.0f);
    __syncthreads();
    const float SQ = 1.00000499998749994f;  // np.sqrt(1+1e-5) as f32
    float a = fc1b[j];
    for (int k = 0; k < HCC; k++) a = fmaf(buf[k], fc1W[k * HCC + j], a);
    a = fmaf(a, bn1g[j] / SQ, bn1b[j]);
    a = fmaxf(a, 0.f);
    buf2[j] = a;
    __syncthreads();
    a = fc2b[j];
    for (int k = 0; k < HCC; k++) a = fmaf(buf2[k], fc2W[k * HCC + j], a);
    a = fmaf(a, bn2g[j] / SQ, bn2b[j]);
    a = fmaxf(a, 0.f);
    buf[j] = a;
    __syncthreads();
    if (j < 2) {
        float o = fc3b[j];
        for (int k = 0; k < HCC; k++) o = fmaf(buf[k], fc3W[k * 2 + j], o);
        out[g * 2 + j] = o;
    }
}

extern "C" void kernel_launch(void* const* d_in, const int* in_sizes, int n_in,
                              void* d_out, int out_size, void* d_ws, size_t ws_size,
                              hipStream_t stream) {
    const float* x      = (const float*)d_in[0];
    const int*   ei     = (const int*)d_in[1];
    const int*   batch  = (const int*)d_in[2];
    const float* l1_Wl  = (const float*)d_in[3];
    const float* l1_bl  = (const float*)d_in[4];
    const float* l1_Wr  = (const float*)d_in[5];
    const float* l1_br  = (const float*)d_in[6];
    const float* l1_att = (const float*)d_in[7];
    const float* l1_bias= (const float*)d_in[8];
    const float* l2_Wl  = (const float*)d_in[9];
    const float* l2_bl  = (const float*)d_in[10];
    const float* l2_Wr  = (const float*)d_in[11];
    const float* l2_br  = (const float*)d_in[12];
    const float* l2_att = (const float*)d_in[13];
    const float* l2_bias= (const float*)d_in[14];
    const float* fc1_W  = (const float*)d_in[15];
    const float* fc1_b  = (const float*)d_in[16];
    const float* bn1_g  = (const float*)d_in[17];
    const float* bn1_b  = (const float*)d_in[18];
    const float* fc2_W  = (const float*)d_in[19];
    const float* fc2_b  = (const float*)d_in[20];
    const float* bn2_g  = (const float*)d_in[21];
    const float* bn2_b  = (const float*)d_in[22];
    const float* fc3_W  = (const float*)d_in[23];
    const float* fc3_b  = (const float*)d_in[24];
    float* out = (float*)d_out;

    float* xl = (float*)d_ws;
    float* xr = xl + (size_t)NN * HCC;
    float* h  = xr + (size_t)NN * HCC;
    int* deg    = (int*)(h + (size_t)NN * HCC);
    int* wptr   = deg + NN;
    int* rowptr = wptr + NN;
    int* col    = rowptr + (NN + 1);

    // CSR build
    k_zero<<<NN / 256, 256, 0, stream>>>(deg);
    k_deg<<<EE / 256, 256, 0, stream>>>(ei, deg);
    k_scan<<<1, 1024, 0, stream>>>(deg, rowptr, wptr);
    k_fill<<<EE / 256, 256, 0, stream>>>(ei, wptr, col);

    // layer 1
    k_lin1<<<NN / 2, 256, 0, stream>>>(x, l1_Wl, l1_bl, l1_Wr, l1_br, xl, xr);
    k_attn<<<NN / 4, 256, 0, stream>>>(rowptr, col, xl, xr, l1_att, l1_bias, h);

    // layer 2
    k_lin2<<<NN / 128, 512, 0, stream>>>(h, l2_Wl, l2_bl, l2_Wr, l2_br, xl, xr);
    k_attn<<<NN / 4, 256, 0, stream>>>(rowptr, col, xl, xr, l2_att, l2_bias, h);

    // pool + MLP head
    k_head<<<GG, 128, 0, stream>>>(h, batch, fc1_W, fc1_b, bn1_g, bn1_b,
                                   fc2_W, fc2_b, bn2_g, bn2_b, fc3_W, fc3_b, out);
}

// Round 4
// 519.894 us; speedup vs baseline: 2.6424x; 1.3201x over previous
//
#include <hip/hip_runtime.h>
#include <math.h>

#define NN 51200
#define EE 1638400
#define GG 512
#define INF 16
#define HCC 128
#define NB 400        // buckets: dst >> 7, 128 nodes each
#define TILE 4096     // edges per k_bin block

// ---------------- CSR build (binned two-level counting sort) ----------------
__global__ __launch_bounds__(512) void k_zb(int* __restrict__ bcnt) {
    if (threadIdx.x < NB) bcnt[threadIdx.x] = 0;
}

__global__ __launch_bounds__(256) void k_hist(const int* __restrict__ ei,
                                              int* __restrict__ bcnt) {
    __shared__ int h[NB];
    for (int i = threadIdx.x; i < NB; i += 256) h[i] = 0;
    __syncthreads();
    int e0 = blockIdx.x * TILE;
#pragma unroll
    for (int s = 0; s < 16; s++) {
        int d = ei[EE + e0 + s * 256 + threadIdx.x];
        atomicAdd(&h[d >> 7], 1);
    }
    __syncthreads();
    for (int i = threadIdx.x; i < NB; i += 256)
        if (h[i]) atomicAdd(&bcnt[i], h[i]);
}

__global__ __launch_bounds__(512) void k_scan2(const int* __restrict__ bcnt,
                                               int* __restrict__ bbase,
                                               int* __restrict__ gcur,
                                               int* __restrict__ rowptr) {
    __shared__ int sc[512];
    int t = threadIdx.x;
    int v = (t < NB) ? bcnt[t] : 0;
    sc[t] = v;
    __syncthreads();
    for (int off = 1; off < 512; off <<= 1) {
        int u = (t >= off) ? sc[t - off] : 0;
        __syncthreads();
        sc[t] += u;
        __syncthreads();
    }
    if (t < NB) { int ex = sc[t] - v; bbase[t] = ex; gcur[t] = ex; }
    if (t == 0) { bbase[NB] = EE; rowptr[NN] = EE; }
}

// tile-local rank by bucket in LDS, then write bucket-sorted runs to binned[]
__global__ __launch_bounds__(512) void k_bin(const int* __restrict__ ei,
                                             int* __restrict__ gcur,
                                             uint2* __restrict__ binned) {
    __shared__ int h[512];
    __shared__ int lexcl[NB], lcur[NB], baseg[NB];
    __shared__ uint2 stage[TILE];
    int t = threadIdx.x;
    h[t] = 0;
    __syncthreads();
    int e0 = blockIdx.x * TILE;
    int sv[8], dv[8];
#pragma unroll
    for (int s = 0; s < 8; s++) {
        int e = e0 + s * 512 + t;
        sv[s] = ei[e];
        dv[s] = ei[EE + e];
        atomicAdd(&h[dv[s] >> 7], 1);
    }
    __syncthreads();
    int myh = h[t];
    for (int off = 1; off < 512; off <<= 1) {
        int u = (t >= off) ? h[t - off] : 0;
        __syncthreads();
        h[t] += u;
        __syncthreads();
    }
    if (t < NB) {
        int ex = h[t] - myh;
        lexcl[t] = ex;
        lcur[t] = ex;
        baseg[t] = atomicAdd(&gcur[t], myh);
    }
    __syncthreads();
#pragma unroll
    for (int s = 0; s < 8; s++) {
        int b = dv[s] >> 7;
        int r = atomicAdd(&lcur[b], 1);
        stage[r] = make_uint2((unsigned)sv[s], (unsigned)dv[s]);
    }
    __syncthreads();
#pragma unroll
    for (int s = 0; s < 8; s++) {
        int idx = s * 512 + t;
        uint2 p = stage[idx];
        int b = (int)(p.y >> 7);
        binned[baseg[b] + idx - lexcl[b]] = p;
    }
}

// per-bucket: node histogram + scan -> rowptr; scatter col within a 16KB window
__global__ __launch_bounds__(256) void k_csr(const uint2* __restrict__ binned,
                                             const int* __restrict__ bbase,
                                             int* __restrict__ rowptr,
                                             int* __restrict__ col) {
    int b = blockIdx.x;
    int base = bbase[b];
    int cnt = bbase[b + 1] - base;
    __shared__ int nh[128], ncur[128];
    int t = threadIdx.x;
    if (t < 128) nh[t] = 0;
    __syncthreads();
    for (int e = t; e < cnt; e += 256) {
        uint2 p = binned[base + e];
        atomicAdd(&nh[p.y & 127], 1);
    }
    __syncthreads();
    int myv = (t < 128) ? nh[t] : 0;
    for (int off = 1; off < 128; off <<= 1) {
        int u = (t >= off && t < 128) ? nh[t - off] : 0;
        __syncthreads();
        if (t < 128) nh[t] += u;
        __syncthreads();
    }
    if (t < 128) {
        int ex = nh[t] - myv;
        rowptr[(b << 7) + t] = base + ex;
        ncur[t] = base + ex;
    }
    __syncthreads();
    for (int e = t; e < cnt; e += 256) {
        uint2 p = binned[base + e];
        int r = atomicAdd(&ncur[p.y & 127], 1);
        col[r] = (int)p.x;
    }
}

// ---------------- layer-1 linear: x[N,16] @ W[16,128] + b ----------------
__global__ __launch_bounds__(256) void k_lin1(const float* __restrict__ x,
                                              const float* __restrict__ Wl,
                                              const float* __restrict__ bl,
                                              const float* __restrict__ Wr,
                                              const float* __restrict__ br,
                                              float* __restrict__ xl,
                                              float* __restrict__ xr) {
    __shared__ float sx[2][INF];
    int j = threadIdx.x & 127;
    int ty = threadIdx.x >> 7;
    int row = blockIdx.x * 2 + ty;
    if (threadIdx.x < 32) {
        int r = blockIdx.x * 2 + (threadIdx.x >> 4);
        sx[threadIdx.x >> 4][threadIdx.x & 15] = x[(size_t)r * INF + (threadIdx.x & 15)];
    }
    __syncthreads();
    float al = bl[j], ar = br[j];
#pragma unroll
    for (int k = 0; k < INF; k++) {
        float xv = sx[ty][k];
        al = fmaf(xv, Wl[k * HCC + j], al);
        ar = fmaf(xv, Wr[k * HCC + j], ar);
    }
    xl[(size_t)row * HCC + j] = al;
    xr[(size_t)row * HCC + j] = ar;
}

// ---------------- layer-2 linear: h[N,128] @ {Wl,Wr}[128,128] + b ----------
#define AST 129
#define BST 260
__global__ __launch_bounds__(512) void k_lin2(const float* __restrict__ hin,
                                              const float* __restrict__ Wl,
                                              const float* __restrict__ bl,
                                              const float* __restrict__ Wr,
                                              const float* __restrict__ br,
                                              float* __restrict__ outl,
                                              float* __restrict__ outr) {
    __shared__ float As[32 * AST];
    __shared__ float Bs[32 * BST];
    const int tid = threadIdx.x;
    const int cx = tid & 31;
    const int cy = tid >> 5;
    const int r0 = blockIdx.x * 128;

    float accL[8][4], accR[8][4];
#pragma unroll
    for (int j = 0; j < 8; j++)
#pragma unroll
        for (int i = 0; i < 4; i++) { accL[j][i] = 0.f; accR[j][i] = 0.f; }

    for (int k0 = 0; k0 < HCC; k0 += 32) {
#pragma unroll
        for (int s = 0; s < 2; s++) {
            int f = tid + 512 * s;
            int row = f >> 3;
            int kk = (f & 7) * 4;
            float4 v = *(const float4*)(hin + (size_t)(r0 + row) * HCC + k0 + kk);
            As[(kk + 0) * AST + row] = v.x;
            As[(kk + 1) * AST + row] = v.y;
            As[(kk + 2) * AST + row] = v.z;
            As[(kk + 3) * AST + row] = v.w;
        }
#pragma unroll
        for (int s = 0; s < 4; s++) {
            int g = tid + 512 * s;
            int kr = g >> 6;
            int c4 = g & 63;
            const float* srcp = (c4 < 32)
                ? (Wl + (size_t)(k0 + kr) * HCC + c4 * 4)
                : (Wr + (size_t)(k0 + kr) * HCC + (c4 - 32) * 4);
            *(float4*)&Bs[kr * BST + c4 * 4] = *(const float4*)srcp;
        }
        __syncthreads();
#pragma unroll 4
        for (int k = 0; k < 32; ++k) {
            float a[8];
#pragma unroll
            for (int j = 0; j < 8; ++j) a[j] = As[k * AST + cy + 16 * j];
            float4 b4l = *(const float4*)&Bs[k * BST + cx * 4];
            float4 b4r = *(const float4*)&Bs[k * BST + 128 + cx * 4];
#pragma unroll
            for (int j = 0; j < 8; ++j) {
                accL[j][0] = fmaf(a[j], b4l.x, accL[j][0]);
                accL[j][1] = fmaf(a[j], b4l.y, accL[j][1]);
                accL[j][2] = fmaf(a[j], b4l.z, accL[j][2]);
                accL[j][3] = fmaf(a[j], b4l.w, accL[j][3]);
                accR[j][0] = fmaf(a[j], b4r.x, accR[j][0]);
                accR[j][1] = fmaf(a[j], b4r.y, accR[j][1]);
                accR[j][2] = fmaf(a[j], b4r.z, accR[j][2]);
                accR[j][3] = fmaf(a[j], b4r.w, accR[j][3]);
            }
        }
        __syncthreads();
    }
    float4 bv_l = *(const float4*)(bl + cx * 4);
    float4 bv_r = *(const float4*)(br + cx * 4);
#pragma unroll
    for (int j = 0; j < 8; ++j) {
        int row = r0 + cy + 16 * j;
        float4 o;
        o.x = accL[j][0] + bv_l.x;
        o.y = accL[j][1] + bv_l.y;
        o.z = accL[j][2] + bv_l.z;
        o.w = accL[j][3] + bv_l.w;
        *(float4*)(outl + (size_t)row * HCC + cx * 4) = o;
        o.x = accR[j][0] + bv_r.x;
        o.y = accR[j][1] + bv_r.y;
        o.z = accR[j][2] + bv_r.z;
        o.w = accR[j][3] + bv_r.w;
        *(float4*)(outr + (size_t)row * HCC + cx * 4) = o;
    }
}

// ---------------- GATv2 attention + aggregate, one wave per node ----------
__global__ __launch_bounds__(256) void k_attn(const int* __restrict__ rowptr,
                                              const int* __restrict__ col,
                                              const float* __restrict__ xl,
                                              const float* __restrict__ xr,
                                              const float* __restrict__ att,
                                              const float* __restrict__ bias,
                                              float* __restrict__ hout) {
    const int wave = threadIdx.x >> 6;
    const int lane = threadIdx.x & 63;
    const int sub = lane >> 5;       // which edge of the pair
    const int sl = lane & 31;        // channel slice
    const int n = blockIdx.x * 4 + wave;

    const float4 xrv = *(const float4*)(xr + (size_t)n * HCC + sl * 4);
    const float4 attv = *(const float4*)(att + sl * 4);
    const unsigned choff = (unsigned)sl * 16u;

    const int base = rowptr[n];
    const int deg = rowptr[n + 1] - base;

    float m = -INFINITY, l = 0.f;
    float4 acc = {0.f, 0.f, 0.f, 0.f};

    for (int i0 = 0; i0 < deg; i0 += 64) {
        int mye = 0;
        if (i0 + lane < deg) mye = col[base + i0 + lane];
        const int cnt = min(64, deg - i0);
        const int pairs = (cnt + 1) >> 1;
#pragma unroll 2
        for (int jj = 0; jj < pairs; ++jj) {
            const int s0 = __builtin_amdgcn_readlane(mye, 2 * jj);
            const int s1 = __builtin_amdgcn_readlane(mye, 2 * jj + 1);
            const bool valid = (2 * jj + sub) < cnt;
            const unsigned a0 = (unsigned)s0 << 9;
            const unsigned a1 = (unsigned)s1 << 9;
            const unsigned voff = (sub ? a1 : a0) + choff;
            const float4 v = *(const float4*)((const char*)xl + voff);
            float e0 = v.x + xrv.x, e1 = v.y + xrv.y, e2 = v.z + xrv.z, e3 = v.w + xrv.w;
            float k0 = fmaf(0.2f, fminf(e0, 0.f), fmaxf(e0, 0.f));
            float k1 = fmaf(0.2f, fminf(e1, 0.f), fmaxf(e1, 0.f));
            float k2 = fmaf(0.2f, fminf(e2, 0.f), fmaxf(e2, 0.f));
            float k3 = fmaf(0.2f, fminf(e3, 0.f), fmaxf(e3, 0.f));
            float p = k0 * attv.x;
            p = fmaf(k1, attv.y, p);
            p = fmaf(k2, attv.z, p);
            p = fmaf(k3, attv.w, p);
            p += __shfl_xor(p, 1);
            p += __shfl_xor(p, 2);
            p += __shfl_xor(p, 4);
            if (!valid) p = -INFINITY;
            const float pmax = fmaxf(p, __shfl_xor(p, 32));
            const float mn = fmaxf(m, pmax);
            const float sc = __expf(m - mn);
            const float wgt = __expf(p - mn);
            l = fmaf(l, sc, wgt);
            acc.x = fmaf(acc.x, sc, wgt * v.x);
            acc.y = fmaf(acc.y, sc, wgt * v.y);
            acc.z = fmaf(acc.z, sc, wgt * v.z);
            acc.w = fmaf(acc.w, sc, wgt * v.w);
            m = mn;
        }
    }
    l += __shfl_xor(l, 32);
    acc.x += __shfl_xor(acc.x, 32);
    acc.y += __shfl_xor(acc.y, 32);
    acc.z += __shfl_xor(acc.z, 32);
    acc.w += __shfl_xor(acc.w, 32);
    const float inv = 1.f / (l + 1e-16f);
    if (sub == 0) {
        const float4 bv = *(const float4*)(bias + sl * 4);
        float4 o;
        o.x = fmaxf(fmaf(acc.x, inv, bv.x), 0.f);
        o.y = fmaxf(fmaf(acc.y, inv, bv.y), 0.f);
        o.z = fmaxf(fmaf(acc.z, inv, bv.z), 0.f);
        o.w = fmaxf(fmaf(acc.w, inv, bv.w), 0.f);
        *(float4*)(hout + (size_t)n * HCC + sl * 4) = o;
    }
}

// ---------------- pool (sorted batch) + MLP head ----------------
__global__ __launch_bounds__(128) void k_head(const float* __restrict__ h,
                                              const int* __restrict__ batch,
                                              const float* __restrict__ fc1W, const float* __restrict__ fc1b,
                                              const float* __restrict__ bn1g, const float* __restrict__ bn1b,
                                              const float* __restrict__ fc2W, const float* __restrict__ fc2b,
                                              const float* __restrict__ bn2g, const float* __restrict__ bn2b,
                                              const float* __restrict__ fc3W, const float* __restrict__ fc3b,
                                              float* __restrict__ out) {
    int g = blockIdx.x;
    int j = threadIdx.x;
    __shared__ float buf[HCC], buf2[HCC];
    int lo = 0, hi = NN;
    while (lo < hi) { int mid = (lo + hi) >> 1; if (batch[mid] < g) lo = mid + 1; else hi = mid; }
    int s = lo;
    lo = 0; hi = NN;
    while (lo < hi) { int mid = (lo + hi) >> 1; if (batch[mid] < g + 1) lo = mid + 1; else hi = mid; }
    int e = lo;
    float sum = 0.f;
    for (int n = s; n < e; n++) sum += h[(size_t)n * HCC + j];
    float cnt = (float)(e - s);
    buf[j] = sum / fmaxf(cnt, 1.0f);
    __syncthreads();
    const float SQ = 1.00000499998749994f;
    float a = fc1b[j];
    for (int k = 0; k < HCC; k++) a = fmaf(buf[k], fc1W[k * HCC + j], a);
    a = fmaf(a, bn1g[j] / SQ, bn1b[j]);
    a = fmaxf(a, 0.f);
    buf2[j] = a;
    __syncthreads();
    a = fc2b[j];
    for (int k = 0; k < HCC; k++) a = fmaf(buf2[k], fc2W[k * HCC + j], a);
    a = fmaf(a, bn2g[j] / SQ, bn2b[j]);
    a = fmaxf(a, 0.f);
    buf[j] = a;
    __syncthreads();
    if (j < 2) {
        float o = fc3b[j];
        for (int k = 0; k < HCC; k++) o = fmaf(buf[k], fc3W[k * 2 + j], o);
        out[g * 2 + j] = o;
    }
}

extern "C" void kernel_launch(void* const* d_in, const int* in_sizes, int n_in,
                              void* d_out, int out_size, void* d_ws, size_t ws_size,
                              hipStream_t stream) {
    const float* x      = (const float*)d_in[0];
    const int*   ei     = (const int*)d_in[1];
    const int*   batch  = (const int*)d_in[2];
    const float* l1_Wl  = (const float*)d_in[3];
    const float* l1_bl  = (const float*)d_in[4];
    const float* l1_Wr  = (const float*)d_in[5];
    const float* l1_br  = (const float*)d_in[6];
    const float* l1_att = (const float*)d_in[7];
    const float* l1_bias= (const float*)d_in[8];
    const float* l2_Wl  = (const float*)d_in[9];
    const float* l2_bl  = (const float*)d_in[10];
    const float* l2_Wr  = (const float*)d_in[11];
    const float* l2_br  = (const float*)d_in[12];
    const float* l2_att = (const float*)d_in[13];
    const float* l2_bias= (const float*)d_in[14];
    const float* fc1_W  = (const float*)d_in[15];
    const float* fc1_b  = (const float*)d_in[16];
    const float* bn1_g  = (const float*)d_in[17];
    const float* bn1_b  = (const float*)d_in[18];
    const float* fc2_W  = (const float*)d_in[19];
    const float* fc2_b  = (const float*)d_in[20];
    const float* bn2_g  = (const float*)d_in[21];
    const float* bn2_b  = (const float*)d_in[22];
    const float* fc3_W  = (const float*)d_in[23];
    const float* fc3_b  = (const float*)d_in[24];
    float* out = (float*)d_out;

    float* xl = (float*)d_ws;
    float* xr = xl + (size_t)NN * HCC;
    float* h  = xr + (size_t)NN * HCC;
    int* rowptr = (int*)(h + (size_t)NN * HCC);
    int* col    = rowptr + (NN + 1);
    int* bcnt   = col + EE;
    int* bbase  = bcnt + NB;
    int* gcur   = bbase + (NB + 1);
    // binned (13 MB) aliases xl (26 MB): CSR build completes before k_lin1 writes xl
    uint2* binned = (uint2*)xl;

    // CSR build
    k_zb<<<1, 512, 0, stream>>>(bcnt);
    k_hist<<<EE / TILE, 256, 0, stream>>>(ei, bcnt);
    k_scan2<<<1, 512, 0, stream>>>(bcnt, bbase, gcur, rowptr);
    k_bin<<<EE / TILE, 512, 0, stream>>>(ei, gcur, binned);
    k_csr<<<NB, 256, 0, stream>>>(binned, bbase, rowptr, col);

    // layer 1
    k_lin1<<<NN / 2, 256, 0, stream>>>(x, l1_Wl, l1_bl, l1_Wr, l1_br, xl, xr);
    k_attn<<<NN / 4, 256, 0, stream>>>(rowptr, col, xl, xr, l1_att, l1_bias, h);

    // layer 2
    k_lin2<<<NN / 128, 512, 0, stream>>>(h, l2_Wl, l2_bl, l2_Wr, l2_br, xl, xr);
    k_attn<<<NN / 4, 256, 0, stream>>>(rowptr, col, xl, xr, l2_att, l2_bias, h);

    // pool + MLP head
    k_head<<<GG, 128, 0, stream>>>(h, batch, fc1_W, fc1_b, bn1_g, bn1_b,
                                   fc2_W, fc2_b, bn2_g, bn2_b, fc3_W, fc3_b, out);
}

// Round 5
// 515.415 us; speedup vs baseline: 2.6653x; 1.0087x over previous
//
#include <hip/hip_runtime.h>
#include <math.h>

#define NN 51200
#define EE 1638400
#define GG 512
#define INF 16
#define HCC 128
#define NB 400        // buckets: dst >> 7, 128 nodes each
#define TILE 4096     // edges per k_bin block

// ---------------- CSR build (binned two-level counting sort) ----------------
__global__ __launch_bounds__(512) void k_zb(int* __restrict__ bcnt) {
    if (threadIdx.x < NB) bcnt[threadIdx.x] = 0;
}

__global__ __launch_bounds__(256) void k_hist(const int* __restrict__ ei,
                                              int* __restrict__ bcnt) {
    __shared__ int h[NB];
    for (int i = threadIdx.x; i < NB; i += 256) h[i] = 0;
    __syncthreads();
    int e0 = blockIdx.x * TILE;
#pragma unroll
    for (int s = 0; s < 16; s++) {
        int d = ei[EE + e0 + s * 256 + threadIdx.x];
        atomicAdd(&h[d >> 7], 1);
    }
    __syncthreads();
    for (int i = threadIdx.x; i < NB; i += 256)
        if (h[i]) atomicAdd(&bcnt[i], h[i]);
}

__global__ __launch_bounds__(512) void k_scan2(const int* __restrict__ bcnt,
                                               int* __restrict__ bbase,
                                               int* __restrict__ gcur,
                                               int* __restrict__ rowptr) {
    __shared__ int sc[512];
    int t = threadIdx.x;
    int v = (t < NB) ? bcnt[t] : 0;
    sc[t] = v;
    __syncthreads();
    for (int off = 1; off < 512; off <<= 1) {
        int u = (t >= off) ? sc[t - off] : 0;
        __syncthreads();
        sc[t] += u;
        __syncthreads();
    }
    if (t < NB) { int ex = sc[t] - v; bbase[t] = ex; gcur[t] = ex; }
    if (t == 0) { bbase[NB] = EE; rowptr[NN] = EE; }
}

// tile-local rank by bucket in LDS, then write bucket-sorted runs to binned[]
__global__ __launch_bounds__(512) void k_bin(const int* __restrict__ ei,
                                             int* __restrict__ gcur,
                                             uint2* __restrict__ binned) {
    __shared__ int h[512];
    __shared__ int lexcl[NB], lcur[NB], baseg[NB];
    __shared__ uint2 stage[TILE];
    int t = threadIdx.x;
    h[t] = 0;
    __syncthreads();
    int e0 = blockIdx.x * TILE;
    int sv[8], dv[8];
#pragma unroll
    for (int s = 0; s < 8; s++) {
        int e = e0 + s * 512 + t;
        sv[s] = ei[e];
        dv[s] = ei[EE + e];
        atomicAdd(&h[dv[s] >> 7], 1);
    }
    __syncthreads();
    int myh = h[t];
    for (int off = 1; off < 512; off <<= 1) {
        int u = (t >= off) ? h[t - off] : 0;
        __syncthreads();
        h[t] += u;
        __syncthreads();
    }
    if (t < NB) {
        int ex = h[t] - myh;
        lexcl[t] = ex;
        lcur[t] = ex;
        baseg[t] = atomicAdd(&gcur[t], myh);
    }
    __syncthreads();
#pragma unroll
    for (int s = 0; s < 8; s++) {
        int b = dv[s] >> 7;
        int r = atomicAdd(&lcur[b], 1);
        stage[r] = make_uint2((unsigned)sv[s], (unsigned)dv[s]);
    }
    __syncthreads();
#pragma unroll
    for (int s = 0; s < 8; s++) {
        int idx = s * 512 + t;
        uint2 p = stage[idx];
        int b = (int)(p.y >> 7);
        binned[baseg[b] + idx - lexcl[b]] = p;
    }
}

// per-bucket: node histogram + scan -> rowptr; scatter col within a 16KB window
__global__ __launch_bounds__(256) void k_csr(const uint2* __restrict__ binned,
                                             const int* __restrict__ bbase,
                                             int* __restrict__ rowptr,
                                             int* __restrict__ col) {
    int b = blockIdx.x;
    int base = bbase[b];
    int cnt = bbase[b + 1] - base;
    __shared__ int nh[128], ncur[128];
    int t = threadIdx.x;
    if (t < 128) nh[t] = 0;
    __syncthreads();
    for (int e = t; e < cnt; e += 256) {
        uint2 p = binned[base + e];
        atomicAdd(&nh[p.y & 127], 1);
    }
    __syncthreads();
    int myv = (t < 128) ? nh[t] : 0;
    for (int off = 1; off < 128; off <<= 1) {
        int u = (t >= off && t < 128) ? nh[t - off] : 0;
        __syncthreads();
        if (t < 128) nh[t] += u;
        __syncthreads();
    }
    if (t < 128) {
        int ex = nh[t] - myv;
        rowptr[(b << 7) + t] = base + ex;
        ncur[t] = base + ex;
    }
    __syncthreads();
    for (int e = t; e < cnt; e += 256) {
        uint2 p = binned[base + e];
        int r = atomicAdd(&ncur[p.y & 127], 1);
        col[r] = (int)p.x;
    }
}

// ---------------- layer-1 linear: x[N,16] @ W[16,128] + b ----------------
__global__ __launch_bounds__(256) void k_lin1(const float* __restrict__ x,
                                              const float* __restrict__ Wl,
                                              const float* __restrict__ bl,
                                              const float* __restrict__ Wr,
                                              const float* __restrict__ br,
                                              float* __restrict__ xl,
                                              float* __restrict__ xr) {
    __shared__ float sx[2][INF];
    int j = threadIdx.x & 127;
    int ty = threadIdx.x >> 7;
    int row = blockIdx.x * 2 + ty;
    if (threadIdx.x < 32) {
        int r = blockIdx.x * 2 + (threadIdx.x >> 4);
        sx[threadIdx.x >> 4][threadIdx.x & 15] = x[(size_t)r * INF + (threadIdx.x & 15)];
    }
    __syncthreads();
    float al = bl[j], ar = br[j];
#pragma unroll
    for (int k = 0; k < INF; k++) {
        float xv = sx[ty][k];
        al = fmaf(xv, Wl[k * HCC + j], al);
        ar = fmaf(xv, Wr[k * HCC + j], ar);
    }
    xl[(size_t)row * HCC + j] = al;
    xr[(size_t)row * HCC + j] = ar;
}

// ---------------- layer-2 linear: h[N,128] @ {Wl,Wr}[128,128] + b ----------
#define AST 129
#define BST 260
__global__ __launch_bounds__(512) void k_lin2(const float* __restrict__ hin,
                                              const float* __restrict__ Wl,
                                              const float* __restrict__ bl,
                                              const float* __restrict__ Wr,
                                              const float* __restrict__ br,
                                              float* __restrict__ outl,
                                              float* __restrict__ outr) {
    __shared__ float As[32 * AST];
    __shared__ float Bs[32 * BST];
    const int tid = threadIdx.x;
    const int cx = tid & 31;
    const int cy = tid >> 5;
    const int r0 = blockIdx.x * 128;

    float accL[8][4], accR[8][4];
#pragma unroll
    for (int j = 0; j < 8; j++)
#pragma unroll
        for (int i = 0; i < 4; i++) { accL[j][i] = 0.f; accR[j][i] = 0.f; }

    for (int k0 = 0; k0 < HCC; k0 += 32) {
#pragma unroll
        for (int s = 0; s < 2; s++) {
            int f = tid + 512 * s;
            int row = f >> 3;
            int kk = (f & 7) * 4;
            float4 v = *(const float4*)(hin + (size_t)(r0 + row) * HCC + k0 + kk);
            As[(kk + 0) * AST + row] = v.x;
            As[(kk + 1) * AST + row] = v.y;
            As[(kk + 2) * AST + row] = v.z;
            As[(kk + 3) * AST + row] = v.w;
        }
#pragma unroll
        for (int s = 0; s < 4; s++) {
            int g = tid + 512 * s;
            int kr = g >> 6;
            int c4 = g & 63;
            const float* srcp = (c4 < 32)
                ? (Wl + (size_t)(k0 + kr) * HCC + c4 * 4)
                : (Wr + (size_t)(k0 + kr) * HCC + (c4 - 32) * 4);
            *(float4*)&Bs[kr * BST + c4 * 4] = *(const float4*)srcp;
        }
        __syncthreads();
#pragma unroll 4
        for (int k = 0; k < 32; ++k) {
            float a[8];
#pragma unroll
            for (int j = 0; j < 8; ++j) a[j] = As[k * AST + cy + 16 * j];
            float4 b4l = *(const float4*)&Bs[k * BST + cx * 4];
            float4 b4r = *(const float4*)&Bs[k * BST + 128 + cx * 4];
#pragma unroll
            for (int j = 0; j < 8; ++j) {
                accL[j][0] = fmaf(a[j], b4l.x, accL[j][0]);
                accL[j][1] = fmaf(a[j], b4l.y, accL[j][1]);
                accL[j][2] = fmaf(a[j], b4l.z, accL[j][2]);
                accL[j][3] = fmaf(a[j], b4l.w, accL[j][3]);
                accR[j][0] = fmaf(a[j], b4r.x, accR[j][0]);
                accR[j][1] = fmaf(a[j], b4r.y, accR[j][1]);
                accR[j][2] = fmaf(a[j], b4r.z, accR[j][2]);
                accR[j][3] = fmaf(a[j], b4r.w, accR[j][3]);
            }
        }
        __syncthreads();
    }
    float4 bv_l = *(const float4*)(bl + cx * 4);
    float4 bv_r = *(const float4*)(br + cx * 4);
#pragma unroll
    for (int j = 0; j < 8; ++j) {
        int row = r0 + cy + 16 * j;
        float4 o;
        o.x = accL[j][0] + bv_l.x;
        o.y = accL[j][1] + bv_l.y;
        o.z = accL[j][2] + bv_l.z;
        o.w = accL[j][3] + bv_l.w;
        *(float4*)(outl + (size_t)row * HCC + cx * 4) = o;
        o.x = accR[j][0] + bv_r.x;
        o.y = accR[j][1] + bv_r.y;
        o.z = accR[j][2] + bv_r.z;
        o.w = accR[j][3] + bv_r.w;
        *(float4*)(outr + (size_t)row * HCC + cx * 4) = o;
    }
}

// ---------------- GATv2 attention + aggregate, one wave per node ----------
// 4 edges per iteration: sub = lane>>4 picks the edge, q = lane&15 picks the
// 8-channel slice (ch 8q..8q+7). Head = 4 consecutive q (xor 1,2 reduce).
// Cross-sub shared max / final combine via xor 16,32. Invalid edges -> -inf.
__global__ __launch_bounds__(256) void k_attn(const int* __restrict__ rowptr,
                                              const int* __restrict__ col,
                                              const float* __restrict__ xl,
                                              const float* __restrict__ xr,
                                              const float* __restrict__ att,
                                              const float* __restrict__ bias,
                                              float* __restrict__ hout) {
    const int wave = threadIdx.x >> 6;
    const int lane = threadIdx.x & 63;
    const int sub = lane >> 4;       // which edge of the quad
    const int q = lane & 15;         // channel slice (8 ch)
    const int n = blockIdx.x * 4 + wave;

    const float4 xrv0 = *(const float4*)(xr + (size_t)n * HCC + q * 8);
    const float4 xrv1 = *(const float4*)(xr + (size_t)n * HCC + q * 8 + 4);
    const float4 att0 = *(const float4*)(att + q * 8);
    const float4 att1 = *(const float4*)(att + q * 8 + 4);
    const unsigned choff = (unsigned)q * 32u;   // byte offset within a row
    const int sub1 = sub & 1, sub2 = sub & 2;

    const int base = rowptr[n];
    const int deg = rowptr[n + 1] - base;

    float m = -INFINITY, l = 0.f;
    float acc[8] = {0.f, 0.f, 0.f, 0.f, 0.f, 0.f, 0.f, 0.f};

    for (int i0 = 0; i0 < deg; i0 += 64) {
        int mye = 0;
        if (i0 + lane < deg) mye = col[base + i0 + lane];
        const int cnt = min(64, deg - i0);
        const int quads = (cnt + 3) >> 2;
#pragma unroll 2
        for (int jj = 0; jj < quads; ++jj) {
            const unsigned a0 = (unsigned)__builtin_amdgcn_readlane(mye, 4 * jj + 0) << 9;
            const unsigned a1 = (unsigned)__builtin_amdgcn_readlane(mye, 4 * jj + 1) << 9;
            const unsigned a2 = (unsigned)__builtin_amdgcn_readlane(mye, 4 * jj + 2) << 9;
            const unsigned a3 = (unsigned)__builtin_amdgcn_readlane(mye, 4 * jj + 3) << 9;
            const unsigned s01 = sub1 ? a1 : a0;
            const unsigned s23 = sub1 ? a3 : a2;
            const unsigned voff = (sub2 ? s23 : s01) + choff;
            const float4 v0 = *(const float4*)((const char*)xl + voff);
            const float4 v1 = *(const float4*)((const char*)xl + voff + 16);
            float e, k, p;
            e = v0.x + xrv0.x; k = fmaf(0.2f, fminf(e, 0.f), fmaxf(e, 0.f)); p = k * att0.x;
            e = v0.y + xrv0.y; k = fmaf(0.2f, fminf(e, 0.f), fmaxf(e, 0.f)); p = fmaf(k, att0.y, p);
            e = v0.z + xrv0.z; k = fmaf(0.2f, fminf(e, 0.f), fmaxf(e, 0.f)); p = fmaf(k, att0.z, p);
            e = v0.w + xrv0.w; k = fmaf(0.2f, fminf(e, 0.f), fmaxf(e, 0.f)); p = fmaf(k, att0.w, p);
            e = v1.x + xrv1.x; k = fmaf(0.2f, fminf(e, 0.f), fmaxf(e, 0.f)); p = fmaf(k, att1.x, p);
            e = v1.y + xrv1.y; k = fmaf(0.2f, fminf(e, 0.f), fmaxf(e, 0.f)); p = fmaf(k, att1.y, p);
            e = v1.z + xrv1.z; k = fmaf(0.2f, fminf(e, 0.f), fmaxf(e, 0.f)); p = fmaf(k, att1.z, p);
            e = v1.w + xrv1.w; k = fmaf(0.2f, fminf(e, 0.f), fmaxf(e, 0.f)); p = fmaf(k, att1.w, p);
            // sum over the head's 4 q-lanes (same sub)
            p += __shfl_xor(p, 1);
            p += __shfl_xor(p, 2);
            if ((4 * jj + sub) >= cnt) p = -INFINITY;
            // shared max across the 4 subs
            float pm = fmaxf(p, __shfl_xor(p, 16));
            pm = fmaxf(pm, __shfl_xor(pm, 32));
            const float mn = fmaxf(m, pm);
            const float sc = __expf(m - mn);     // m=-inf first iter -> 0
            const float wgt = __expf(p - mn);    // invalid -> 0
            l = fmaf(l, sc, wgt);
            acc[0] = fmaf(acc[0], sc, wgt * v0.x);
            acc[1] = fmaf(acc[1], sc, wgt * v0.y);
            acc[2] = fmaf(acc[2], sc, wgt * v0.z);
            acc[3] = fmaf(acc[3], sc, wgt * v0.w);
            acc[4] = fmaf(acc[4], sc, wgt * v1.x);
            acc[5] = fmaf(acc[5], sc, wgt * v1.y);
            acc[6] = fmaf(acc[6], sc, wgt * v1.z);
            acc[7] = fmaf(acc[7], sc, wgt * v1.w);
            m = mn;
        }
    }
    // combine the four subs (they share the same m)
    l += __shfl_xor(l, 16);
    l += __shfl_xor(l, 32);
#pragma unroll
    for (int i = 0; i < 8; i++) {
        acc[i] += __shfl_xor(acc[i], 16);
        acc[i] += __shfl_xor(acc[i], 32);
    }
    const float inv = 1.f / (l + 1e-16f);
    if (sub == 0) {
        const float4 b0 = *(const float4*)(bias + q * 8);
        const float4 b1 = *(const float4*)(bias + q * 8 + 4);
        float4 o0, o1;
        o0.x = fmaxf(fmaf(acc[0], inv, b0.x), 0.f);
        o0.y = fmaxf(fmaf(acc[1], inv, b0.y), 0.f);
        o0.z = fmaxf(fmaf(acc[2], inv, b0.z), 0.f);
        o0.w = fmaxf(fmaf(acc[3], inv, b0.w), 0.f);
        o1.x = fmaxf(fmaf(acc[4], inv, b1.x), 0.f);
        o1.y = fmaxf(fmaf(acc[5], inv, b1.y), 0.f);
        o1.z = fmaxf(fmaf(acc[6], inv, b1.z), 0.f);
        o1.w = fmaxf(fmaf(acc[7], inv, b1.w), 0.f);
        *(float4*)(hout + (size_t)n * HCC + q * 8) = o0;
        *(float4*)(hout + (size_t)n * HCC + q * 8 + 4) = o1;
    }
}

// ---------------- pool (sorted batch) + MLP head ----------------
__global__ __launch_bounds__(128) void k_head(const float* __restrict__ h,
                                              const int* __restrict__ batch,
                                              const float* __restrict__ fc1W, const float* __restrict__ fc1b,
                                              const float* __restrict__ bn1g, const float* __restrict__ bn1b,
                                              const float* __restrict__ fc2W, const float* __restrict__ fc2b,
                                              const float* __restrict__ bn2g, const float* __restrict__ bn2b,
                                              const float* __restrict__ fc3W, const float* __restrict__ fc3b,
                                              float* __restrict__ out) {
    int g = blockIdx.x;
    int j = threadIdx.x;
    __shared__ float buf[HCC], buf2[HCC];
    int lo = 0, hi = NN;
    while (lo < hi) { int mid = (lo + hi) >> 1; if (batch[mid] < g) lo = mid + 1; else hi = mid; }
    int s = lo;
    lo = 0; hi = NN;
    while (lo < hi) { int mid = (lo + hi) >> 1; if (batch[mid] < g + 1) lo = mid + 1; else hi = mid; }
    int e = lo;
    float sum = 0.f;
    for (int n = s; n < e; n++) sum += h[(size_t)n * HCC + j];
    float cnt = (float)(e - s);
    buf[j] = sum / fmaxf(cnt, 1.0f);
    __syncthreads();
    const float SQ = 1.00000499998749994f;
    float a = fc1b[j];
    for (int k = 0; k < HCC; k++) a = fmaf(buf[k], fc1W[k * HCC + j], a);
    a = fmaf(a, bn1g[j] / SQ, bn1b[j]);
    a = fmaxf(a, 0.f);
    buf2[j] = a;
    __syncthreads();
    a = fc2b[j];
    for (int k = 0; k < HCC; k++) a = fmaf(buf2[k], fc2W[k * HCC + j], a);
    a = fmaf(a, bn2g[j] / SQ, bn2b[j]);
    a = fmaxf(a, 0.f);
    buf[j] = a;
    __syncthreads();
    if (j < 2) {
        float o = fc3b[j];
        for (int k = 0; k < HCC; k++) o = fmaf(buf[k], fc3W[k * 2 + j], o);
        out[g * 2 + j] = o;
    }
}

extern "C" void kernel_launch(void* const* d_in, const int* in_sizes, int n_in,
                              void* d_out, int out_size, void* d_ws, size_t ws_size,
                              hipStream_t stream) {
    const float* x      = (const float*)d_in[0];
    const int*   ei     = (const int*)d_in[1];
    const int*   batch  = (const int*)d_in[2];
    const float* l1_Wl  = (const float*)d_in[3];
    const float* l1_bl  = (const float*)d_in[4];
    const float* l1_Wr  = (const float*)d_in[5];
    const float* l1_br  = (const float*)d_in[6];
    const float* l1_att = (const float*)d_in[7];
    const float* l1_bias= (const float*)d_in[8];
    const float* l2_Wl  = (const float*)d_in[9];
    const float* l2_bl  = (const float*)d_in[10];
    const float* l2_Wr  = (const float*)d_in[11];
    const float* l2_br  = (const float*)d_in[12];
    const float* l2_att = (const float*)d_in[13];
    const float* l2_bias= (const float*)d_in[14];
    const float* fc1_W  = (const float*)d_in[15];
    const float* fc1_b  = (const float*)d_in[16];
    const float* bn1_g  = (const float*)d_in[17];
    const float* bn1_b  = (const float*)d_in[18];
    const float* fc2_W  = (const float*)d_in[19];
    const float* fc2_b  = (const float*)d_in[20];
    const float* bn2_g  = (const float*)d_in[21];
    const float* bn2_b  = (const float*)d_in[22];
    const float* fc3_W  = (const float*)d_in[23];
    const float* fc3_b  = (const float*)d_in[24];
    float* out = (float*)d_out;

    float* xl = (float*)d_ws;
    float* xr = xl + (size_t)NN * HCC;
    float* h  = xr + (size_t)NN * HCC;
    int* rowptr = (int*)(h + (size_t)NN * HCC);
    int* col    = rowptr + (NN + 1);
    int* bcnt   = col + EE;
    int* bbase  = bcnt + NB;
    int* gcur   = bbase + (NB + 1);
    // binned (13 MB) aliases xl (26 MB): CSR build completes before k_lin1 writes xl
    uint2* binned = (uint2*)xl;

    // CSR build
    k_zb<<<1, 512, 0, stream>>>(bcnt);
    k_hist<<<EE / TILE, 256, 0, stream>>>(ei, bcnt);
    k_scan2<<<1, 512, 0, stream>>>(bcnt, bbase, gcur, rowptr);
    k_bin<<<EE / TILE, 512, 0, stream>>>(ei, gcur, binned);
    k_csr<<<NB, 256, 0, stream>>>(binned, bbase, rowptr, col);

    // layer 1
    k_lin1<<<NN / 2, 256, 0, stream>>>(x, l1_Wl, l1_bl, l1_Wr, l1_br, xl, xr);
    k_attn<<<NN / 4, 256, 0, stream>>>(rowptr, col, xl, xr, l1_att, l1_bias, h);

    // layer 2
    k_lin2<<<NN / 128, 512, 0, stream>>>(h, l2_Wl, l2_bl, l2_Wr, l2_br, xl, xr);
    k_attn<<<NN / 4, 256, 0, stream>>>(rowptr, col, xl, xr, l2_att, l2_bias, h);

    // pool + MLP head
    k_head<<<GG, 128, 0, stream>>>(h, batch, fc1_W, fc1_b, bn1_g, bn1_b,
                                   fc2_W, fc2_b, bn2_g, bn2_b, fc3_W, fc3_b, out);
}

// Round 6
// 513.084 us; speedup vs baseline: 2.6775x; 1.0045x over previous
//
#include <hip/hip_runtime.h>
#include <math.h>

#define NN 51200
#define EE 1638400
#define GG 512
#define INF 16
#define HCC 128
#define NB 400        // buckets: dst >> 7, 128 nodes each
#define TILE 4096     // edges per k_bin block

typedef float vf2 __attribute__((ext_vector_type(2)));
#define FMA2 __builtin_elementwise_fma
#define MIN2 __builtin_elementwise_min
#define MAX2 __builtin_elementwise_max

// ---------------- CSR build (binned two-level counting sort) ----------------
__global__ __launch_bounds__(256) void k_hist(const int* __restrict__ ei,
                                              int* __restrict__ bcnt) {
    __shared__ int h[NB];
    for (int i = threadIdx.x; i < NB; i += 256) h[i] = 0;
    __syncthreads();
    int e0 = blockIdx.x * TILE;
#pragma unroll
    for (int s = 0; s < 16; s++) {
        int d = ei[EE + e0 + s * 256 + threadIdx.x];
        atomicAdd(&h[d >> 7], 1);
    }
    __syncthreads();
    for (int i = threadIdx.x; i < NB; i += 256)
        if (h[i]) atomicAdd(&bcnt[i], h[i]);
}

__global__ __launch_bounds__(512) void k_scan2(const int* __restrict__ bcnt,
                                               int* __restrict__ bbase,
                                               int* __restrict__ gcur,
                                               int* __restrict__ rowptr) {
    __shared__ int sc[512];
    int t = threadIdx.x;
    int v = (t < NB) ? bcnt[t] : 0;
    sc[t] = v;
    __syncthreads();
    for (int off = 1; off < 512; off <<= 1) {
        int u = (t >= off) ? sc[t - off] : 0;
        __syncthreads();
        sc[t] += u;
        __syncthreads();
    }
    if (t < NB) { int ex = sc[t] - v; bbase[t] = ex; gcur[t] = ex; }
    if (t == 0) { bbase[NB] = EE; rowptr[NN] = EE; }
}

// tile-local rank by bucket in LDS, then write bucket-sorted runs to binned[]
__global__ __launch_bounds__(512) void k_bin(const int* __restrict__ ei,
                                             int* __restrict__ gcur,
                                             uint2* __restrict__ binned) {
    __shared__ int h[512];
    __shared__ int lexcl[NB], lcur[NB], baseg[NB];
    __shared__ uint2 stage[TILE];
    int t = threadIdx.x;
    h[t] = 0;
    __syncthreads();
    int e0 = blockIdx.x * TILE;
    int sv[8], dv[8];
#pragma unroll
    for (int s = 0; s < 8; s++) {
        int e = e0 + s * 512 + t;
        sv[s] = ei[e];
        dv[s] = ei[EE + e];
        atomicAdd(&h[dv[s] >> 7], 1);
    }
    __syncthreads();
    int myh = h[t];
    for (int off = 1; off < 512; off <<= 1) {
        int u = (t >= off) ? h[t - off] : 0;
        __syncthreads();
        h[t] += u;
        __syncthreads();
    }
    if (t < NB) {
        int ex = h[t] - myh;
        lexcl[t] = ex;
        lcur[t] = ex;
        baseg[t] = atomicAdd(&gcur[t], myh);
    }
    __syncthreads();
#pragma unroll
    for (int s = 0; s < 8; s++) {
        int b = dv[s] >> 7;
        int r = atomicAdd(&lcur[b], 1);
        stage[r] = make_uint2((unsigned)sv[s], (unsigned)dv[s]);
    }
    __syncthreads();
#pragma unroll
    for (int s = 0; s < 8; s++) {
        int idx = s * 512 + t;
        uint2 p = stage[idx];
        int b = (int)(p.y >> 7);
        binned[baseg[b] + idx - lexcl[b]] = p;
    }
}

// per-bucket: node histogram + scan -> rowptr; scatter col within a 16KB window
__global__ __launch_bounds__(256) void k_csr(const uint2* __restrict__ binned,
                                             const int* __restrict__ bbase,
                                             int* __restrict__ rowptr,
                                             int* __restrict__ col) {
    int b = blockIdx.x;
    int base = bbase[b];
    int cnt = bbase[b + 1] - base;
    __shared__ int nh[128], ncur[128];
    int t = threadIdx.x;
    if (t < 128) nh[t] = 0;
    __syncthreads();
    for (int e = t; e < cnt; e += 256) {
        uint2 p = binned[base + e];
        atomicAdd(&nh[p.y & 127], 1);
    }
    __syncthreads();
    int myv = (t < 128) ? nh[t] : 0;
    for (int off = 1; off < 128; off <<= 1) {
        int u = (t >= off && t < 128) ? nh[t - off] : 0;
        __syncthreads();
        if (t < 128) nh[t] += u;
        __syncthreads();
    }
    if (t < 128) {
        int ex = nh[t] - myv;
        rowptr[(b << 7) + t] = base + ex;
        ncur[t] = base + ex;
    }
    __syncthreads();
    for (int e = t; e < cnt; e += 256) {
        uint2 p = binned[base + e];
        int r = atomicAdd(&ncur[p.y & 127], 1);
        col[r] = (int)p.x;
    }
}

// ---------------- layer-1 linear: x[N,16] @ W[16,128] + b ----------------
__global__ __launch_bounds__(256) void k_lin1(const float* __restrict__ x,
                                              const float* __restrict__ Wl,
                                              const float* __restrict__ bl,
                                              const float* __restrict__ Wr,
                                              const float* __restrict__ br,
                                              float* __restrict__ xl,
                                              float* __restrict__ xr) {
    __shared__ float sx[2][INF];
    int j = threadIdx.x & 127;
    int ty = threadIdx.x >> 7;
    int row = blockIdx.x * 2 + ty;
    if (threadIdx.x < 32) {
        int r = blockIdx.x * 2 + (threadIdx.x >> 4);
        sx[threadIdx.x >> 4][threadIdx.x & 15] = x[(size_t)r * INF + (threadIdx.x & 15)];
    }
    __syncthreads();
    float al = bl[j], ar = br[j];
#pragma unroll
    for (int k = 0; k < INF; k++) {
        float xv = sx[ty][k];
        al = fmaf(xv, Wl[k * HCC + j], al);
        ar = fmaf(xv, Wr[k * HCC + j], ar);
    }
    xl[(size_t)row * HCC + j] = al;
    xr[(size_t)row * HCC + j] = ar;
}

// ---------------- layer-2 linear: h[N,128] @ {Wl,Wr}[128,128] + b ----------
#define AST 129
#define BST 260
__global__ __launch_bounds__(512) void k_lin2(const float* __restrict__ hin,
                                              const float* __restrict__ Wl,
                                              const float* __restrict__ bl,
                                              const float* __restrict__ Wr,
                                              const float* __restrict__ br,
                                              float* __restrict__ outl,
                                              float* __restrict__ outr) {
    __shared__ float As[32 * AST];
    __shared__ float Bs[32 * BST];
    const int tid = threadIdx.x;
    const int cx = tid & 31;
    const int cy = tid >> 5;
    const int r0 = blockIdx.x * 128;

    float accL[8][4], accR[8][4];
#pragma unroll
    for (int j = 0; j < 8; j++)
#pragma unroll
        for (int i = 0; i < 4; i++) { accL[j][i] = 0.f; accR[j][i] = 0.f; }

    for (int k0 = 0; k0 < HCC; k0 += 32) {
#pragma unroll
        for (int s = 0; s < 2; s++) {
            int f = tid + 512 * s;
            int row = f >> 3;
            int kk = (f & 7) * 4;
            float4 v = *(const float4*)(hin + (size_t)(r0 + row) * HCC + k0 + kk);
            As[(kk + 0) * AST + row] = v.x;
            As[(kk + 1) * AST + row] = v.y;
            As[(kk + 2) * AST + row] = v.z;
            As[(kk + 3) * AST + row] = v.w;
        }
#pragma unroll
        for (int s = 0; s < 4; s++) {
            int g = tid + 512 * s;
            int kr = g >> 6;
            int c4 = g & 63;
            const float* srcp = (c4 < 32)
                ? (Wl + (size_t)(k0 + kr) * HCC + c4 * 4)
                : (Wr + (size_t)(k0 + kr) * HCC + (c4 - 32) * 4);
            *(float4*)&Bs[kr * BST + c4 * 4] = *(const float4*)srcp;
        }
        __syncthreads();
#pragma unroll 4
        for (int k = 0; k < 32; ++k) {
            float a[8];
#pragma unroll
            for (int j = 0; j < 8; ++j) a[j] = As[k * AST + cy + 16 * j];
            float4 b4l = *(const float4*)&Bs[k * BST + cx * 4];
            float4 b4r = *(const float4*)&Bs[k * BST + 128 + cx * 4];
#pragma unroll
            for (int j = 0; j < 8; ++j) {
                accL[j][0] = fmaf(a[j], b4l.x, accL[j][0]);
                accL[j][1] = fmaf(a[j], b4l.y, accL[j][1]);
                accL[j][2] = fmaf(a[j], b4l.z, accL[j][2]);
                accL[j][3] = fmaf(a[j], b4l.w, accL[j][3]);
                accR[j][0] = fmaf(a[j], b4r.x, accR[j][0]);
                accR[j][1] = fmaf(a[j], b4r.y, accR[j][1]);
                accR[j][2] = fmaf(a[j], b4r.z, accR[j][2]);
                accR[j][3] = fmaf(a[j], b4r.w, accR[j][3]);
            }
        }
        __syncthreads();
    }
    float4 bv_l = *(const float4*)(bl + cx * 4);
    float4 bv_r = *(const float4*)(br + cx * 4);
#pragma unroll
    for (int j = 0; j < 8; ++j) {
        int row = r0 + cy + 16 * j;
        float4 o;
        o.x = accL[j][0] + bv_l.x;
        o.y = accL[j][1] + bv_l.y;
        o.z = accL[j][2] + bv_l.z;
        o.w = accL[j][3] + bv_l.w;
        *(float4*)(outl + (size_t)row * HCC + cx * 4) = o;
        o.x = accR[j][0] + bv_r.x;
        o.y = accR[j][1] + bv_r.y;
        o.z = accR[j][2] + bv_r.z;
        o.w = accR[j][3] + bv_r.w;
        *(float4*)(outr + (size_t)row * HCC + cx * 4) = o;
    }
}

// ---------------- GATv2 attention + aggregate, one wave per node ----------
// 4 edges per iteration: sub = lane>>4 picks the edge, q = lane&15 picks the
// 8-channel slice. Packed-f32 (v_pk_*) elementwise math; src id via single
// ds_bpermute shfl. Head = 4 consecutive q (xor 1,2). Cross-sub via xor 16,32.
__global__ __launch_bounds__(256) void k_attn(const int* __restrict__ rowptr,
                                              const int* __restrict__ col,
                                              const float* __restrict__ xl,
                                              const float* __restrict__ xr,
                                              const float* __restrict__ att,
                                              const float* __restrict__ bias,
                                              float* __restrict__ hout) {
    const int wave = threadIdx.x >> 6;
    const int lane = threadIdx.x & 63;
    const int sub = lane >> 4;       // which edge of the quad
    const int q = lane & 15;         // channel slice (8 ch)
    const int n = blockIdx.x * 4 + wave;

    const float4 xrv0 = *(const float4*)(xr + (size_t)n * HCC + q * 8);
    const float4 xrv1 = *(const float4*)(xr + (size_t)n * HCC + q * 8 + 4);
    const float4 at0 = *(const float4*)(att + q * 8);
    const float4 at1 = *(const float4*)(att + q * 8 + 4);
    const vf2 xr01 = {xrv0.x, xrv0.y}, xr23 = {xrv0.z, xrv0.w};
    const vf2 xr45 = {xrv1.x, xrv1.y}, xr67 = {xrv1.z, xrv1.w};
    const vf2 at01 = {at0.x, at0.y}, at23 = {at0.z, at0.w};
    const vf2 at45 = {at1.x, at1.y}, at67 = {at1.z, at1.w};
    const vf2 Z2 = {0.f, 0.f}, C2 = {0.2f, 0.2f};
    const unsigned choff = (unsigned)q * 32u;   // byte offset within a row

    const int base = rowptr[n];
    const int deg = rowptr[n + 1] - base;

    float m = -INFINITY, l = 0.f;
    vf2 a01 = Z2, a23 = Z2, a45 = Z2, a67 = Z2;

    for (int i0 = 0; i0 < deg; i0 += 64) {
        int mye = 0;
        if (i0 + lane < deg) mye = col[base + i0 + lane];
        const int cnt = min(64, deg - i0);
        const int quads = (cnt + 3) >> 2;
#pragma unroll 2
        for (int jj = 0; jj < quads; ++jj) {
            const int src = __shfl(mye, 4 * jj + sub);
            const unsigned voff = ((unsigned)src << 9) + choff;
            const float4 v0 = *(const float4*)((const char*)xl + voff);
            const float4 v1 = *(const float4*)((const char*)xl + voff + 16);
            const vf2 v01 = {v0.x, v0.y}, v23 = {v0.z, v0.w};
            const vf2 v45 = {v1.x, v1.y}, v67 = {v1.z, v1.w};
            vf2 e, kk, p2;
            e = v01 + xr01; kk = FMA2(C2, MIN2(e, Z2), MAX2(e, Z2)); p2 = kk * at01;
            e = v23 + xr23; kk = FMA2(C2, MIN2(e, Z2), MAX2(e, Z2)); p2 = FMA2(kk, at23, p2);
            e = v45 + xr45; kk = FMA2(C2, MIN2(e, Z2), MAX2(e, Z2)); p2 = FMA2(kk, at45, p2);
            e = v67 + xr67; kk = FMA2(C2, MIN2(e, Z2), MAX2(e, Z2)); p2 = FMA2(kk, at67, p2);
            float p = p2.x + p2.y;
            // sum over the head's 4 q-lanes (same sub)
            p += __shfl_xor(p, 1);
            p += __shfl_xor(p, 2);
            if ((4 * jj + sub) >= cnt) p = -INFINITY;
            // shared max across the 4 subs
            float pm = fmaxf(p, __shfl_xor(p, 16));
            pm = fmaxf(pm, __shfl_xor(pm, 32));
            const float mn = fmaxf(m, pm);
            const float sc = __expf(m - mn);     // m=-inf first iter -> 0
            const float wgt = __expf(p - mn);    // invalid -> 0
            l = fmaf(l, sc, wgt);
            const vf2 s2 = {sc, sc}, w2 = {wgt, wgt};
            a01 = FMA2(a01, s2, w2 * v01);
            a23 = FMA2(a23, s2, w2 * v23);
            a45 = FMA2(a45, s2, w2 * v45);
            a67 = FMA2(a67, s2, w2 * v67);
            m = mn;
        }
    }
    // combine the four subs (they share the same m)
    l += __shfl_xor(l, 16);
    l += __shfl_xor(l, 32);
    float af[8] = {a01.x, a01.y, a23.x, a23.y, a45.x, a45.y, a67.x, a67.y};
#pragma unroll
    for (int i = 0; i < 8; i++) {
        af[i] += __shfl_xor(af[i], 16);
        af[i] += __shfl_xor(af[i], 32);
    }
    const float inv = 1.f / (l + 1e-16f);
    if (sub == 0) {
        const float4 b0 = *(const float4*)(bias + q * 8);
        const float4 b1 = *(const float4*)(bias + q * 8 + 4);
        float4 o0, o1;
        o0.x = fmaxf(fmaf(af[0], inv, b0.x), 0.f);
        o0.y = fmaxf(fmaf(af[1], inv, b0.y), 0.f);
        o0.z = fmaxf(fmaf(af[2], inv, b0.z), 0.f);
        o0.w = fmaxf(fmaf(af[3], inv, b0.w), 0.f);
        o1.x = fmaxf(fmaf(af[4], inv, b1.x), 0.f);
        o1.y = fmaxf(fmaf(af[5], inv, b1.y), 0.f);
        o1.z = fmaxf(fmaf(af[6], inv, b1.z), 0.f);
        o1.w = fmaxf(fmaf(af[7], inv, b1.w), 0.f);
        *(float4*)(hout + (size_t)n * HCC + q * 8) = o0;
        *(float4*)(hout + (size_t)n * HCC + q * 8 + 4) = o1;
    }
}

// ---------------- pool (sorted batch) + MLP head ----------------
__global__ __launch_bounds__(128) void k_head(const float* __restrict__ h,
                                              const int* __restrict__ batch,
                                              const float* __restrict__ fc1W, const float* __restrict__ fc1b,
                                              const float* __restrict__ bn1g, const float* __restrict__ bn1b,
                                              const float* __restrict__ fc2W, const float* __restrict__ fc2b,
                                              const float* __restrict__ bn2g, const float* __restrict__ bn2b,
                                              const float* __restrict__ fc3W, const float* __restrict__ fc3b,
                                              float* __restrict__ out) {
    int g = blockIdx.x;
    int j = threadIdx.x;
    __shared__ float buf[HCC], buf2[HCC];
    int lo = 0, hi = NN;
    while (lo < hi) { int mid = (lo + hi) >> 1; if (batch[mid] < g) lo = mid + 1; else hi = mid; }
    int s = lo;
    lo = 0; hi = NN;
    while (lo < hi) { int mid = (lo + hi) >> 1; if (batch[mid] < g + 1) lo = mid + 1; else hi = mid; }
    int e = lo;
    float sum = 0.f;
    for (int n = s; n < e; n++) sum += h[(size_t)n * HCC + j];
    float cnt = (float)(e - s);
    buf[j] = sum / fmaxf(cnt, 1.0f);
    __syncthreads();
    const float SQ = 1.00000499998749994f;
    float a = fc1b[j];
    for (int k = 0; k < HCC; k++) a = fmaf(buf[k], fc1W[k * HCC + j], a);
    a = fmaf(a, bn1g[j] / SQ, bn1b[j]);
    a = fmaxf(a, 0.f);
    buf2[j] = a;
    __syncthreads();
    a = fc2b[j];
    for (int k = 0; k < HCC; k++) a = fmaf(buf2[k], fc2W[k * HCC + j], a);
    a = fmaf(a, bn2g[j] / SQ, bn2b[j]);
    a = fmaxf(a, 0.f);
    buf[j] = a;
    __syncthreads();
    if (j < 2) {
        float o = fc3b[j];
        for (int k = 0; k < HCC; k++) o = fmaf(buf[k], fc3W[k * 2 + j], o);
        out[g * 2 + j] = o;
    }
}

extern "C" void kernel_launch(void* const* d_in, const int* in_sizes, int n_in,
                              void* d_out, int out_size, void* d_ws, size_t ws_size,
                              hipStream_t stream) {
    const float* x      = (const float*)d_in[0];
    const int*   ei     = (const int*)d_in[1];
    const int*   batch  = (const int*)d_in[2];
    const float* l1_Wl  = (const float*)d_in[3];
    const float* l1_bl  = (const float*)d_in[4];
    const float* l1_Wr  = (const float*)d_in[5];
    const float* l1_br  = (const float*)d_in[6];
    const float* l1_att = (const float*)d_in[7];
    const float* l1_bias= (const float*)d_in[8];
    const float* l2_Wl  = (const float*)d_in[9];
    const float* l2_bl  = (const float*)d_in[10];
    const float* l2_Wr  = (const float*)d_in[11];
    const float* l2_br  = (const float*)d_in[12];
    const float* l2_att = (const float*)d_in[13];
    const float* l2_bias= (const float*)d_in[14];
    const float* fc1_W  = (const float*)d_in[15];
    const float* fc1_b  = (const float*)d_in[16];
    const float* bn1_g  = (const float*)d_in[17];
    const float* bn1_b  = (const float*)d_in[18];
    const float* fc2_W  = (const float*)d_in[19];
    const float* fc2_b  = (const float*)d_in[20];
    const float* bn2_g  = (const float*)d_in[21];
    const float* bn2_b  = (const float*)d_in[22];
    const float* fc3_W  = (const float*)d_in[23];
    const float* fc3_b  = (const float*)d_in[24];
    float* out = (float*)d_out;

    float* xl = (float*)d_ws;
    float* xr = xl + (size_t)NN * HCC;
    float* h  = xr + (size_t)NN * HCC;
    int* rowptr = (int*)(h + (size_t)NN * HCC);
    int* col    = rowptr + (NN + 1);
    int* bcnt   = col + EE;
    int* bbase  = bcnt + NB;
    int* gcur   = bbase + (NB + 1);
    // binned (13 MB) aliases xl (26 MB): CSR build completes before k_lin1 writes xl
    uint2* binned = (uint2*)xl;

    // CSR build
    hipMemsetAsync(bcnt, 0, NB * sizeof(int), stream);
    k_hist<<<EE / TILE, 256, 0, stream>>>(ei, bcnt);
    k_scan2<<<1, 512, 0, stream>>>(bcnt, bbase, gcur, rowptr);
    k_bin<<<EE / TILE, 512, 0, stream>>>(ei, gcur, binned);
    k_csr<<<NB, 256, 0, stream>>>(binned, bbase, rowptr, col);

    // layer 1
    k_lin1<<<NN / 2, 256, 0, stream>>>(x, l1_Wl, l1_bl, l1_Wr, l1_br, xl, xr);
    k_attn<<<NN / 4, 256, 0, stream>>>(rowptr, col, xl, xr, l1_att, l1_bias, h);

    // layer 2
    k_lin2<<<NN / 128, 512, 0, stream>>>(h, l2_Wl, l2_bl, l2_Wr, l2_br, xl, xr);
    k_attn<<<NN / 4, 256, 0, stream>>>(rowptr, col, xl, xr, l2_att, l2_bias, h);

    // pool + MLP head
    k_head<<<GG, 128, 0, stream>>>(h, batch, fc1_W, fc1_b, bn1_g, bn1_b,
                                   fc2_W, fc2_b, bn2_g, bn2_b, fc3_W, fc3_b, out);
}

// Round 7
// 511.427 us; speedup vs baseline: 2.6861x; 1.0032x over previous
//
#include <hip/hip_runtime.h>
#include <math.h>

#define NN 51200
#define EE 1638400
#define GG 512
#define INF 16
#define HCC 128
#define NB 400        // buckets: dst >> 7, 128 nodes each
#define TILE 4096     // edges per k_bin block

typedef float vf2 __attribute__((ext_vector_type(2)));
#define FMA2 __builtin_elementwise_fma
#define MIN2 __builtin_elementwise_min
#define MAX2 __builtin_elementwise_max

// ---------------- CSR build (binned two-level counting sort) ----------------
__global__ __launch_bounds__(256) void k_hist(const int* __restrict__ ei,
                                              int* __restrict__ bcnt) {
    __shared__ int h[NB];
    for (int i = threadIdx.x; i < NB; i += 256) h[i] = 0;
    __syncthreads();
    int e0 = blockIdx.x * TILE;
#pragma unroll
    for (int s = 0; s < 16; s++) {
        int d = ei[EE + e0 + s * 256 + threadIdx.x];
        atomicAdd(&h[d >> 7], 1);
    }
    __syncthreads();
    for (int i = threadIdx.x; i < NB; i += 256)
        if (h[i]) atomicAdd(&bcnt[i], h[i]);
}

__global__ __launch_bounds__(512) void k_scan2(const int* __restrict__ bcnt,
                                               int* __restrict__ bbase,
                                               int* __restrict__ gcur,
                                               int* __restrict__ rowptr) {
    __shared__ int sc[512];
    int t = threadIdx.x;
    int v = (t < NB) ? bcnt[t] : 0;
    sc[t] = v;
    __syncthreads();
    for (int off = 1; off < 512; off <<= 1) {
        int u = (t >= off) ? sc[t - off] : 0;
        __syncthreads();
        sc[t] += u;
        __syncthreads();
    }
    if (t < NB) { int ex = sc[t] - v; bbase[t] = ex; gcur[t] = ex; }
    if (t == 0) { bbase[NB] = EE; rowptr[NN] = EE; }
}

// tile-local rank by bucket in LDS, then write bucket-sorted runs to binned[]
__global__ __launch_bounds__(512) void k_bin(const int* __restrict__ ei,
                                             int* __restrict__ gcur,
                                             uint2* __restrict__ binned) {
    __shared__ int h[512];
    __shared__ int lexcl[NB], lcur[NB], baseg[NB];
    __shared__ uint2 stage[TILE];
    int t = threadIdx.x;
    h[t] = 0;
    __syncthreads();
    int e0 = blockIdx.x * TILE;
    int sv[8], dv[8];
#pragma unroll
    for (int s = 0; s < 8; s++) {
        int e = e0 + s * 512 + t;
        sv[s] = ei[e];
        dv[s] = ei[EE + e];
        atomicAdd(&h[dv[s] >> 7], 1);
    }
    __syncthreads();
    int myh = h[t];
    for (int off = 1; off < 512; off <<= 1) {
        int u = (t >= off) ? h[t - off] : 0;
        __syncthreads();
        h[t] += u;
        __syncthreads();
    }
    if (t < NB) {
        int ex = h[t] - myh;
        lexcl[t] = ex;
        lcur[t] = ex;
        baseg[t] = atomicAdd(&gcur[t], myh);
    }
    __syncthreads();
#pragma unroll
    for (int s = 0; s < 8; s++) {
        int b = dv[s] >> 7;
        int r = atomicAdd(&lcur[b], 1);
        stage[r] = make_uint2((unsigned)sv[s], (unsigned)dv[s]);
    }
    __syncthreads();
#pragma unroll
    for (int s = 0; s < 8; s++) {
        int idx = s * 512 + t;
        uint2 p = stage[idx];
        int b = (int)(p.y >> 7);
        binned[baseg[b] + idx - lexcl[b]] = p;
    }
}

// per-bucket: node histogram + scan -> rowptr; scatter col within a 16KB window
__global__ __launch_bounds__(256) void k_csr(const uint2* __restrict__ binned,
                                             const int* __restrict__ bbase,
                                             int* __restrict__ rowptr,
                                             int* __restrict__ col) {
    int b = blockIdx.x;
    int base = bbase[b];
    int cnt = bbase[b + 1] - base;
    __shared__ int nh[128], ncur[128];
    int t = threadIdx.x;
    if (t < 128) nh[t] = 0;
    __syncthreads();
    for (int e = t; e < cnt; e += 256) {
        uint2 p = binned[base + e];
        atomicAdd(&nh[p.y & 127], 1);
    }
    __syncthreads();
    int myv = (t < 128) ? nh[t] : 0;
    for (int off = 1; off < 128; off <<= 1) {
        int u = (t >= off && t < 128) ? nh[t - off] : 0;
        __syncthreads();
        if (t < 128) nh[t] += u;
        __syncthreads();
    }
    if (t < 128) {
        int ex = nh[t] - myv;
        rowptr[(b << 7) + t] = base + ex;
        ncur[t] = base + ex;
    }
    __syncthreads();
    for (int e = t; e < cnt; e += 256) {
        uint2 p = binned[base + e];
        int r = atomicAdd(&ncur[p.y & 127], 1);
        col[r] = (int)p.x;
    }
}

// ---------------- layer-1 linear: x[N,16] @ W[16,128] + b ----------------
__global__ __launch_bounds__(256) void k_lin1(const float* __restrict__ x,
                                              const float* __restrict__ Wl,
                                              const float* __restrict__ bl,
                                              const float* __restrict__ Wr,
                                              const float* __restrict__ br,
                                              float* __restrict__ xl,
                                              float* __restrict__ xr) {
    __shared__ float sx[2][INF];
    int j = threadIdx.x & 127;
    int ty = threadIdx.x >> 7;
    int row = blockIdx.x * 2 + ty;
    if (threadIdx.x < 32) {
        int r = blockIdx.x * 2 + (threadIdx.x >> 4);
        sx[threadIdx.x >> 4][threadIdx.x & 15] = x[(size_t)r * INF + (threadIdx.x & 15)];
    }
    __syncthreads();
    float al = bl[j], ar = br[j];
#pragma unroll
    for (int k = 0; k < INF; k++) {
        float xv = sx[ty][k];
        al = fmaf(xv, Wl[k * HCC + j], al);
        ar = fmaf(xv, Wr[k * HCC + j], ar);
    }
    xl[(size_t)row * HCC + j] = al;
    xr[(size_t)row * HCC + j] = ar;
}

// ---------------- layer-2 linear: h[N,128] @ {Wl,Wr}[128,128] + b ----------
#define AST 129
#define BST 260
__global__ __launch_bounds__(512) void k_lin2(const float* __restrict__ hin,
                                              const float* __restrict__ Wl,
                                              const float* __restrict__ bl,
                                              const float* __restrict__ Wr,
                                              const float* __restrict__ br,
                                              float* __restrict__ outl,
                                              float* __restrict__ outr) {
    __shared__ float As[32 * AST];
    __shared__ float Bs[32 * BST];
    const int tid = threadIdx.x;
    const int cx = tid & 31;
    const int cy = tid >> 5;
    const int r0 = blockIdx.x * 128;

    float accL[8][4], accR[8][4];
#pragma unroll
    for (int j = 0; j < 8; j++)
#pragma unroll
        for (int i = 0; i < 4; i++) { accL[j][i] = 0.f; accR[j][i] = 0.f; }

    for (int k0 = 0; k0 < HCC; k0 += 32) {
#pragma unroll
        for (int s = 0; s < 2; s++) {
            int f = tid + 512 * s;
            int row = f >> 3;
            int kk = (f & 7) * 4;
            float4 v = *(const float4*)(hin + (size_t)(r0 + row) * HCC + k0 + kk);
            As[(kk + 0) * AST + row] = v.x;
            As[(kk + 1) * AST + row] = v.y;
            As[(kk + 2) * AST + row] = v.z;
            As[(kk + 3) * AST + row] = v.w;
        }
#pragma unroll
        for (int s = 0; s < 4; s++) {
            int g = tid + 512 * s;
            int kr = g >> 6;
            int c4 = g & 63;
            const float* srcp = (c4 < 32)
                ? (Wl + (size_t)(k0 + kr) * HCC + c4 * 4)
                : (Wr + (size_t)(k0 + kr) * HCC + (c4 - 32) * 4);
            *(float4*)&Bs[kr * BST + c4 * 4] = *(const float4*)srcp;
        }
        __syncthreads();
#pragma unroll 4
        for (int k = 0; k < 32; ++k) {
            float a[8];
#pragma unroll
            for (int j = 0; j < 8; ++j) a[j] = As[k * AST + cy + 16 * j];
            float4 b4l = *(const float4*)&Bs[k * BST + cx * 4];
            float4 b4r = *(const float4*)&Bs[k * BST + 128 + cx * 4];
#pragma unroll
            for (int j = 0; j < 8; ++j) {
                accL[j][0] = fmaf(a[j], b4l.x, accL[j][0]);
                accL[j][1] = fmaf(a[j], b4l.y, accL[j][1]);
                accL[j][2] = fmaf(a[j], b4l.z, accL[j][2]);
                accL[j][3] = fmaf(a[j], b4l.w, accL[j][3]);
                accR[j][0] = fmaf(a[j], b4r.x, accR[j][0]);
                accR[j][1] = fmaf(a[j], b4r.y, accR[j][1]);
                accR[j][2] = fmaf(a[j], b4r.z, accR[j][2]);
                accR[j][3] = fmaf(a[j], b4r.w, accR[j][3]);
            }
        }
        __syncthreads();
    }
    float4 bv_l = *(const float4*)(bl + cx * 4);
    float4 bv_r = *(const float4*)(br + cx * 4);
#pragma unroll
    for (int j = 0; j < 8; ++j) {
        int row = r0 + cy + 16 * j;
        float4 o;
        o.x = accL[j][0] + bv_l.x;
        o.y = accL[j][1] + bv_l.y;
        o.z = accL[j][2] + bv_l.z;
        o.w = accL[j][3] + bv_l.w;
        *(float4*)(outl + (size_t)row * HCC + cx * 4) = o;
        o.x = accR[j][0] + bv_r.x;
        o.y = accR[j][1] + bv_r.y;
        o.z = accR[j][2] + bv_r.z;
        o.w = accR[j][3] + bv_r.w;
        *(float4*)(outr + (size_t)row * HCC + cx * 4) = o;
    }
}

// ---------------- GATv2 attention + aggregate, one wave per node ----------
// 16 edges per softmax event: 4 quads' gathers issued back-to-back (4x MLP),
// scores computed in parallel, then ONE cross-sub max + ONE rescale.
// sub = lane>>4 picks edge-in-quad, q = lane&15 picks the 8-channel slice.
__global__ __launch_bounds__(256) void k_attn(const int* __restrict__ rowptr,
                                              const int* __restrict__ col,
                                              const float* __restrict__ xl,
                                              const float* __restrict__ xr,
                                              const float* __restrict__ att,
                                              const float* __restrict__ bias,
                                              float* __restrict__ hout) {
    const int wave = threadIdx.x >> 6;
    const int lane = threadIdx.x & 63;
    const int sub = lane >> 4;       // which edge of the quad
    const int q = lane & 15;         // channel slice (8 ch)
    const int n = blockIdx.x * 4 + wave;

    const float4 xrv0 = *(const float4*)(xr + (size_t)n * HCC + q * 8);
    const float4 xrv1 = *(const float4*)(xr + (size_t)n * HCC + q * 8 + 4);
    const float4 at0 = *(const float4*)(att + q * 8);
    const float4 at1 = *(const float4*)(att + q * 8 + 4);
    const vf2 xr01 = {xrv0.x, xrv0.y}, xr23 = {xrv0.z, xrv0.w};
    const vf2 xr45 = {xrv1.x, xrv1.y}, xr67 = {xrv1.z, xrv1.w};
    const vf2 at01 = {at0.x, at0.y}, at23 = {at0.z, at0.w};
    const vf2 at45 = {at1.x, at1.y}, at67 = {at1.z, at1.w};
    const vf2 Z2 = {0.f, 0.f}, C2 = {0.2f, 0.2f};
    const unsigned choff = (unsigned)q * 32u;   // byte offset within a row

    const int base = rowptr[n];
    const int deg = rowptr[n + 1] - base;

    float m = -INFINITY, l = 0.f;
    vf2 a01 = Z2, a23 = Z2, a45 = Z2, a67 = Z2;

    for (int i0 = 0; i0 < deg; i0 += 64) {
        int mye = 0;
        if (i0 + lane < deg) mye = col[base + i0 + lane];
        const int cnt = min(64, deg - i0);
        const int groups = (cnt + 15) >> 4;
        for (int g = 0; g < groups; ++g) {
            vf2 v01[4], v23[4], v45[4], v67[4];
            // 4 independent gathers in flight
#pragma unroll
            for (int k = 0; k < 4; ++k) {
                const int src = __shfl(mye, 16 * g + 4 * k + sub);
                const unsigned voff = ((unsigned)src << 9) + choff;
                const float4 v0 = *(const float4*)((const char*)xl + voff);
                const float4 v1 = *(const float4*)((const char*)xl + voff + 16);
                v01[k] = (vf2){v0.x, v0.y}; v23[k] = (vf2){v0.z, v0.w};
                v45[k] = (vf2){v1.x, v1.y}; v67[k] = (vf2){v1.z, v1.w};
            }
            // 4 independent score chains
            float p[4];
#pragma unroll
            for (int k = 0; k < 4; ++k) {
                vf2 e, kk, p2;
                e = v01[k] + xr01; kk = FMA2(C2, MIN2(e, Z2), MAX2(e, Z2)); p2 = kk * at01;
                e = v23[k] + xr23; kk = FMA2(C2, MIN2(e, Z2), MAX2(e, Z2)); p2 = FMA2(kk, at23, p2);
                e = v45[k] + xr45; kk = FMA2(C2, MIN2(e, Z2), MAX2(e, Z2)); p2 = FMA2(kk, at45, p2);
                e = v67[k] + xr67; kk = FMA2(C2, MIN2(e, Z2), MAX2(e, Z2)); p2 = FMA2(kk, at67, p2);
                float pp = p2.x + p2.y;
                pp += __shfl_xor(pp, 1);
                pp += __shfl_xor(pp, 2);
                if ((16 * g + 4 * k + sub) >= cnt) pp = -INFINITY;
                p[k] = pp;
            }
            // ONE softmax event per 16 edges
            float pm = fmaxf(fmaxf(p[0], p[1]), fmaxf(p[2], p[3]));
            pm = fmaxf(pm, __shfl_xor(pm, 16));
            pm = fmaxf(pm, __shfl_xor(pm, 32));
            const float mn = fmaxf(m, pm);
            const float sc = __expf(m - mn);     // m=-inf first group -> 0
            const float w0 = __expf(p[0] - mn);  // invalid -> 0
            const float w1 = __expf(p[1] - mn);
            const float w2 = __expf(p[2] - mn);
            const float w3 = __expf(p[3] - mn);
            l = fmaf(l, sc, (w0 + w1) + (w2 + w3));
            const vf2 S = {sc, sc};
            const vf2 W0 = {w0, w0}, W1 = {w1, w1}, W2 = {w2, w2}, W3 = {w3, w3};
            a01 = FMA2(W3, v01[3], FMA2(W2, v01[2], FMA2(W1, v01[1], FMA2(W0, v01[0], a01 * S))));
            a23 = FMA2(W3, v23[3], FMA2(W2, v23[2], FMA2(W1, v23[1], FMA2(W0, v23[0], a23 * S))));
            a45 = FMA2(W3, v45[3], FMA2(W2, v45[2], FMA2(W1, v45[1], FMA2(W0, v45[0], a45 * S))));
            a67 = FMA2(W3, v67[3], FMA2(W2, v67[2], FMA2(W1, v67[1], FMA2(W0, v67[0], a67 * S))));
            m = mn;
        }
    }
    // combine the four subs (they share the same m)
    l += __shfl_xor(l, 16);
    l += __shfl_xor(l, 32);
    float af[8] = {a01.x, a01.y, a23.x, a23.y, a45.x, a45.y, a67.x, a67.y};
#pragma unroll
    for (int i = 0; i < 8; i++) {
        af[i] += __shfl_xor(af[i], 16);
        af[i] += __shfl_xor(af[i], 32);
    }
    const float inv = 1.f / (l + 1e-16f);
    if (sub == 0) {
        const float4 b0 = *(const float4*)(bias + q * 8);
        const float4 b1 = *(const float4*)(bias + q * 8 + 4);
        float4 o0, o1;
        o0.x = fmaxf(fmaf(af[0], inv, b0.x), 0.f);
        o0.y = fmaxf(fmaf(af[1], inv, b0.y), 0.f);
        o0.z = fmaxf(fmaf(af[2], inv, b0.z), 0.f);
        o0.w = fmaxf(fmaf(af[3], inv, b0.w), 0.f);
        o1.x = fmaxf(fmaf(af[4], inv, b1.x), 0.f);
        o1.y = fmaxf(fmaf(af[5], inv, b1.y), 0.f);
        o1.z = fmaxf(fmaf(af[6], inv, b1.z), 0.f);
        o1.w = fmaxf(fmaf(af[7], inv, b1.w), 0.f);
        *(float4*)(hout + (size_t)n * HCC + q * 8) = o0;
        *(float4*)(hout + (size_t)n * HCC + q * 8 + 4) = o1;
    }
}

// ---------------- pool (sorted batch) + MLP head ----------------
__global__ __launch_bounds__(128) void k_head(const float* __restrict__ h,
                                              const int* __restrict__ batch,
                                              const float* __restrict__ fc1W, const float* __restrict__ fc1b,
                                              const float* __restrict__ bn1g, const float* __restrict__ bn1b,
                                              const float* __restrict__ fc2W, const float* __restrict__ fc2b,
                                              const float* __restrict__ bn2g, const float* __restrict__ bn2b,
                                              const float* __restrict__ fc3W, const float* __restrict__ fc3b,
                                              float* __restrict__ out) {
    int g = blockIdx.x;
    int j = threadIdx.x;
    __shared__ float buf[HCC], buf2[HCC];
    int lo = 0, hi = NN;
    while (lo < hi) { int mid = (lo + hi) >> 1; if (batch[mid] < g) lo = mid + 1; else hi = mid; }
    int s = lo;
    lo = 0; hi = NN;
    while (lo < hi) { int mid = (lo + hi) >> 1; if (batch[mid] < g + 1) lo = mid + 1; else hi = mid; }
    int e = lo;
    float sum = 0.f;
    for (int n = s; n < e; n++) sum += h[(size_t)n * HCC + j];
    float cnt = (float)(e - s);
    buf[j] = sum / fmaxf(cnt, 1.0f);
    __syncthreads();
    const float SQ = 1.00000499998749994f;
    float a = fc1b[j];
    for (int k = 0; k < HCC; k++) a = fmaf(buf[k], fc1W[k * HCC + j], a);
    a = fmaf(a, bn1g[j] / SQ, bn1b[j]);
    a = fmaxf(a, 0.f);
    buf2[j] = a;
    __syncthreads();
    a = fc2b[j];
    for (int k = 0; k < HCC; k++) a = fmaf(buf2[k], fc2W[k * HCC + j], a);
    a = fmaf(a, bn2g[j] / SQ, bn2b[j]);
    a = fmaxf(a, 0.f);
    buf[j] = a;
    __syncthreads();
    if (j < 2) {
        float o = fc3b[j];
        for (int k = 0; k < HCC; k++) o = fmaf(buf[k], fc3W[k * 2 + j], o);
        out[g * 2 + j] = o;
    }
}

extern "C" void kernel_launch(void* const* d_in, const int* in_sizes, int n_in,
                              void* d_out, int out_size, void* d_ws, size_t ws_size,
                              hipStream_t stream) {
    const float* x      = (const float*)d_in[0];
    const int*   ei     = (const int*)d_in[1];
    const int*   batch  = (const int*)d_in[2];
    const float* l1_Wl  = (const float*)d_in[3];
    const float* l1_bl  = (const float*)d_in[4];
    const float* l1_Wr  = (const float*)d_in[5];
    const float* l1_br  = (const float*)d_in[6];
    const float* l1_att = (const float*)d_in[7];
    const float* l1_bias= (const float*)d_in[8];
    const float* l2_Wl  = (const float*)d_in[9];
    const float* l2_bl  = (const float*)d_in[10];
    const float* l2_Wr  = (const float*)d_in[11];
    const float* l2_br  = (const float*)d_in[12];
    const float* l2_att = (const float*)d_in[13];
    const float* l2_bias= (const float*)d_in[14];
    const float* fc1_W  = (const float*)d_in[15];
    const float* fc1_b  = (const float*)d_in[16];
    const float* bn1_g  = (const float*)d_in[17];
    const float* bn1_b  = (const float*)d_in[18];
    const float* fc2_W  = (const float*)d_in[19];
    const float* fc2_b  = (const float*)d_in[20];
    const float* bn2_g  = (const float*)d_in[21];
    const float* bn2_b  = (const float*)d_in[22];
    const float* fc3_W  = (const float*)d_in[23];
    const float* fc3_b  = (const float*)d_in[24];
    float* out = (float*)d_out;

    float* xl = (float*)d_ws;
    float* xr = xl + (size_t)NN * HCC;
    float* h  = xr + (size_t)NN * HCC;
    int* rowptr = (int*)(h + (size_t)NN * HCC);
    int* col    = rowptr + (NN + 1);
    int* bcnt   = col + EE;
    int* bbase  = bcnt + NB;
    int* gcur   = bbase + (NB + 1);
    // binned (13 MB) aliases xl (26 MB): CSR build completes before k_lin1 writes xl
    uint2* binned = (uint2*)xl;

    // CSR build
    hipMemsetAsync(bcnt, 0, NB * sizeof(int), stream);
    k_hist<<<EE / TILE, 256, 0, stream>>>(ei, bcnt);
    k_scan2<<<1, 512, 0, stream>>>(bcnt, bbase, gcur, rowptr);
    k_bin<<<EE / TILE, 512, 0, stream>>>(ei, gcur, binned);
    k_csr<<<NB, 256, 0, stream>>>(binned, bbase, rowptr, col);

    // layer 1
    k_lin1<<<NN / 2, 256, 0, stream>>>(x, l1_Wl, l1_bl, l1_Wr, l1_br, xl, xr);
    k_attn<<<NN / 4, 256, 0, stream>>>(rowptr, col, xl, xr, l1_att, l1_bias, h);

    // layer 2
    k_lin2<<<NN / 128, 512, 0, stream>>>(h, l2_Wl, l2_bl, l2_Wr, l2_br, xl, xr);
    k_attn<<<NN / 4, 256, 0, stream>>>(rowptr, col, xl, xr, l2_att, l2_bias, h);

    // pool + MLP head
    k_head<<<GG, 128, 0, stream>>>(h, batch, fc1_W, fc1_b, bn1_g, bn1_b,
                                   fc2_W, fc2_b, bn2_g, bn2_b, fc3_W, fc3_b, out);
}